// Round 7
// baseline (617.617 us; speedup 1.0000x reference)
//
#include <hip/hip_runtime.h>
#include <math.h>

#define NPG 28
#define EPG 64
#define NB  256
#define NG  512
#define NN  14336
#define NE  32768
#define TEMPINV 10.0f
#define SINK_ITERS 20
#define CW 0.9f

typedef unsigned int uint;
typedef unsigned short ushort;
typedef __attribute__((ext_vector_type(8))) __bf16 bf16x8;
typedef __attribute__((ext_vector_type(4))) float f32x4;

__device__ __forceinline__ ushort f2bf(float x) {
    uint u = __float_as_uint(x);
    u += 0x7fffu + ((u >> 16) & 1u);
    return (ushort)(u >> 16);
}
__device__ __forceinline__ float bflo(uint w) { return __uint_as_float(w << 16); }
__device__ __forceinline__ float bfhi(uint w) { return __uint_as_float(w & 0xffff0000u); }
__device__ __forceinline__ uint relu_sum_pk(uint w1, uint w2, uint w3) {
    float lo = fmaxf(bflo(w1) + bflo(w2) + bflo(w3), 0.f);
    float hi = fmaxf(bfhi(w1) + bfhi(w2) + bfhi(w3), 0.f);
    return (uint)f2bf(lo) | ((uint)f2bf(hi) << 16);
}
__device__ __forceinline__ uint add_pk(uint w1, uint w2) {
    return (uint)f2bf(bflo(w1) + bflo(w2)) | ((uint)f2bf(bfhi(w1) + bfhi(w2)) << 16);
}
__device__ __forceinline__ f32x4 mfma16(bf16x8 a, bf16x8 b, f32x4 c) {
    return __builtin_amdgcn_mfma_f32_16x16x32_bf16(a, b, c, 0, 0, 0);
}

// ---------------------------------------------------------------------------
// Fused message kernel v4: one block = (graph, pass). blockIdx.y = pass
// (0 = forward, 1 = reverse). HP pass-half computed by MFMA into LDS, then
// layer-2 GEMM with A built from LDS HP gathers + coalesced EC2 reads.
// SEG: LDS segment-sum -> aggF/aggR (bf16). EMIT: -> EMF/EMR (fp32, +own bias).
// LDS: HPs 29.1KB + acc_s 14.3KB (SEG) + idx 0.5KB = 34KB -> 4 blocks/CU.
// ---------------------------------------------------------------------------
template<bool SEG>
__global__ __launch_bounds__(256, 4) void msg_fused(
    const ushort* __restrict__ h_bf, const ushort* __restrict__ EC2,
    const ushort* __restrict__ WhpL,
    const ushort* __restrict__ W2fL, const ushort* __restrict__ W2rL,
    const float* __restrict__ b2f, const float* __restrict__ b2r,
    const int* __restrict__ from_idx, const int* __restrict__ to_idx,
    ushort* __restrict__ aggF, ushort* __restrict__ aggR,
    float* __restrict__ EMF, float* __restrict__ EMR)
{
    __shared__ ushort HPs[NPG * 520];        // pass-half: 28 x 512, stride 520
    __shared__ float acc_s[SEG ? NPG * 128 : 64];
    __shared__ int fl[64], tl[64];
    const int g = blockIdx.x;
    const int p = blockIdx.y;
    const int tid = threadIdx.x;
    const int w = tid >> 6, lane = tid & 63;
    const int li = lane & 15, quad = lane >> 4;

    if (tid < 64) {
        fl[tid] = from_idx[g * 64 + tid] - g * NPG;
        tl[tid] = to_idx[g * 64 + tid] - g * NPG;
    }
    if (SEG) {
        for (int u = tid; u < NPG * 128; u += 256) acc_s[u] = 0.f;
    }

    // h A-frags straight from global (h_bf is L2-resident; rows >= NPG guarded)
    uint4 ha[2][4];
#pragma unroll
    for (int mi = 0; mi < 2; ++mi) {
        const int row = mi * 16 + li;
        const int rr = (row < NPG) ? row : 0;   // pad rows: harmless reread
        const ushort* src = h_bf + ((size_t)g * NPG + rr) * 128 + quad * 8;
#pragma unroll
        for (int kb = 0; kb < 4; ++kb) ha[mi][kb] = *(const uint4*)(src + kb * 32);
    }

    {   // ---- HP pass-half: global cols [p*512, p*512+512) -> HPs local cols
        const int colw = w * 128;
#pragma unroll
        for (int ni = 0; ni < 8; ++ni) {
            const int col = colw + ni * 16 + li;          // local col [0,512)
            const ushort* pb = WhpL + (size_t)(p * 512 + col) * 32 + quad * 8;
            f32x4 c0 = f32x4{0.f, 0.f, 0.f, 0.f};
            f32x4 c1 = f32x4{0.f, 0.f, 0.f, 0.f};
#pragma unroll
            for (int kb = 0; kb < 4; ++kb) {
                const bf16x8 b = __builtin_bit_cast(bf16x8,
                    *(const uint4*)(pb + (size_t)kb * 32768));
                c0 = mfma16(__builtin_bit_cast(bf16x8, ha[0][kb]), b, c0);
                c1 = mfma16(__builtin_bit_cast(bf16x8, ha[1][kb]), b, c1);
            }
#pragma unroll
            for (int r = 0; r < 4; ++r) {
                const int r0 = quad * 4 + r;
                HPs[r0 * 520 + col] = f2bf(c0[r]);
                const int r1 = 16 + quad * 4 + r;
                if (r1 < NPG) HPs[r1 * 520 + col] = f2bf(c1[r]);
            }
        }
    }
    __syncthreads();

    // ---- layer-2 GEMM (K=256, out 64x32 per wave over 64 edges)
    f32x4 acc[4][2];
#pragma unroll
    for (int i = 0; i < 4; ++i)
#pragma unroll
        for (int j = 0; j < 2; ++j) acc[i][j] = f32x4{0.f, 0.f, 0.f, 0.f};

    int ad1[4], ad2[4], ade[4];
#pragma unroll
    for (int mi = 0; mi < 4; ++mi) {
        const int e = mi * 16 + li;
        const int i1 = p ? tl[e] : fl[e];
        const int i2 = p ? fl[e] : tl[e];
        ad1[mi] = i1 * 520 + quad * 8;
        ad2[mi] = i2 * 520 + 256 + quad * 8;
        ade[mi] = e * 32 + quad * 8;
    }
    const ushort* ecb = EC2 + (size_t)(g * 2 + p) * 16384;
    const ushort* W2L = p ? W2rL : W2fL;
    const ushort* pb0 = W2L + (size_t)(w * 32 + li) * 32 + quad * 8;
    const ushort* pb1 = W2L + (size_t)(w * 32 + 16 + li) * 32 + quad * 8;
#pragma unroll
    for (int kb = 0; kb < 8; ++kb) {
        const bf16x8 b0 = __builtin_bit_cast(bf16x8, *(const uint4*)(pb0 + (size_t)kb * 4096));
        const bf16x8 b1 = __builtin_bit_cast(bf16x8, *(const uint4*)(pb1 + (size_t)kb * 4096));
        bf16x8 a[4];
#pragma unroll
        for (int mi = 0; mi < 4; ++mi) {
            const uint4 u1 = *(const uint4*)&HPs[ad1[mi] + kb * 32];
            const uint4 u2 = *(const uint4*)&HPs[ad2[mi] + kb * 32];
            const uint4 ue = *(const uint4*)(ecb + kb * 2048 + ade[mi]);
            uint4 o;
            o.x = relu_sum_pk(u1.x, u2.x, ue.x);
            o.y = relu_sum_pk(u1.y, u2.y, ue.y);
            o.z = relu_sum_pk(u1.z, u2.z, ue.z);
            o.w = relu_sum_pk(u1.w, u2.w, ue.w);
            a[mi] = __builtin_bit_cast(bf16x8, o);
        }
#pragma unroll
        for (int mi = 0; mi < 4; ++mi) {
            acc[mi][0] = mfma16(a[mi], b0, acc[mi][0]);
            acc[mi][1] = mfma16(a[mi], b1, acc[mi][1]);
        }
    }

    if (SEG) {
        const int* targ = p ? fl : tl;
        const float* bias = p ? b2r : b2f;
        const int n0 = w * 32;
        const float bv0 = bias[n0 + li], bv1 = bias[n0 + 16 + li];
#pragma unroll
        for (int mi = 0; mi < 4; ++mi)
#pragma unroll
            for (int r = 0; r < 4; ++r) {
                const int loc = targ[mi * 16 + quad * 4 + r];
                atomicAdd(&acc_s[loc * 128 + n0 + li], acc[mi][0][r] + bv0);
                atomicAdd(&acc_s[loc * 128 + n0 + 16 + li], acc[mi][1][r] + bv1);
            }
        __syncthreads();
        ushort* dst = (p ? aggR : aggF) + (size_t)g * (NPG * 128);
        for (int u = tid; u < NPG * 128; u += 256) dst[u] = f2bf(acc_s[u]);
    } else {
        float* out = p ? EMR : EMF;
        const float* bias = p ? b2r : b2f;
        const int n0 = w * 32;
        const float bv0 = bias[n0 + li], bv1 = bias[n0 + 16 + li];
#pragma unroll
        for (int mi = 0; mi < 4; ++mi)
#pragma unroll
            for (int r = 0; r < 4; ++r) {
                const int e = g * 64 + mi * 16 + quad * 4 + r;
                out[(size_t)e * 128 + n0 + li] = acc[mi][0][r] + bv0;
                out[(size_t)e * 128 + n0 + 16 + li] = acc[mi][1][r] + bv1;
            }
    }
}

// ---------------------------------------------------------------------------
// Fused update MLP: 16-row tiles; phase-1 A = [aggF+aggR | h].
// ---------------------------------------------------------------------------
__global__ __launch_bounds__(256) void upd_fused(
    const ushort* __restrict__ aggF, const ushort* __restrict__ aggR,
    const ushort* __restrict__ hbf,
    const ushort* __restrict__ UW1T, const float* __restrict__ b1,
    const ushort* __restrict__ UW2T, const float* __restrict__ b2,
    float* __restrict__ h, ushort* __restrict__ h_bf_out)
{
    __shared__ ushort hid_s[16][264];
    const int tid = threadIdx.x;
    const int w = tid >> 6, lane = tid & 63;
    const int li = lane & 15, quad = lane >> 4;
    const int m0 = blockIdx.x * 16;

    {   // phase 1
        const int n0 = w * 64;
        f32x4 acc[4];
#pragma unroll
        for (int j = 0; j < 4; ++j) acc[j] = f32x4{0.f, 0.f, 0.f, 0.f};
        const ushort* pb[4];
#pragma unroll
        for (int ni = 0; ni < 4; ++ni)
            pb[ni] = UW1T + (size_t)(n0 + ni * 16 + li) * 256 + quad * 8;
        const ushort* pa_f = aggF + (size_t)(m0 + li) * 128 + quad * 8;
        const ushort* pa_r = aggR + (size_t)(m0 + li) * 128 + quad * 8;
        const ushort* pa_h = hbf + (size_t)(m0 + li) * 128 + quad * 8;
#pragma unroll
        for (int kb = 0; kb < 8; ++kb) {
            bf16x8 a;
            if (kb < 4) {
                const uint4 uf = *(const uint4*)(pa_f + kb * 32);
                const uint4 ur = *(const uint4*)(pa_r + kb * 32);
                uint4 o;
                o.x = add_pk(uf.x, ur.x);
                o.y = add_pk(uf.y, ur.y);
                o.z = add_pk(uf.z, ur.z);
                o.w = add_pk(uf.w, ur.w);
                a = __builtin_bit_cast(bf16x8, o);
            } else {
                a = __builtin_bit_cast(bf16x8, *(const uint4*)(pa_h + (kb - 4) * 32));
            }
            bf16x8 b[4];
#pragma unroll
            for (int ni = 0; ni < 4; ++ni)
                b[ni] = __builtin_bit_cast(bf16x8, *(const uint4*)(pb[ni] + kb * 32));
#pragma unroll
            for (int ni = 0; ni < 4; ++ni) acc[ni] = mfma16(a, b[ni], acc[ni]);
        }
#pragma unroll
        for (int ni = 0; ni < 4; ++ni) {
            const float bv = b1[n0 + ni * 16 + li];
#pragma unroll
            for (int r = 0; r < 4; ++r)
                hid_s[quad * 4 + r][n0 + ni * 16 + li] =
                    f2bf(fmaxf(acc[ni][r] + bv, 0.f));
        }
    }
    __syncthreads();
    {   // phase 2
        const int n0 = w * 32;
        f32x4 acc[2];
#pragma unroll
        for (int j = 0; j < 2; ++j) acc[j] = f32x4{0.f, 0.f, 0.f, 0.f};
        const ushort* pb[2];
#pragma unroll
        for (int ni = 0; ni < 2; ++ni)
            pb[ni] = UW2T + (size_t)(n0 + ni * 16 + li) * 256 + quad * 8;
#pragma unroll
        for (int kb = 0; kb < 8; ++kb) {
            const bf16x8 a = __builtin_bit_cast(bf16x8,
                *(const uint4*)&hid_s[li][kb * 32 + quad * 8]);
            bf16x8 b[2];
#pragma unroll
            for (int ni = 0; ni < 2; ++ni)
                b[ni] = __builtin_bit_cast(bf16x8, *(const uint4*)(pb[ni] + kb * 32));
#pragma unroll
            for (int ni = 0; ni < 2; ++ni) acc[ni] = mfma16(a, b[ni], acc[ni]);
        }
#pragma unroll
        for (int ni = 0; ni < 2; ++ni) {
            const int ncol = n0 + ni * 16 + li;
            const float bv = b2[ncol];
#pragma unroll
            for (int r = 0; r < 4; ++r) {
                const int row = m0 + quad * 4 + r;
                const size_t idx = (size_t)row * 128 + ncol;
                const float nh = h[idx] + acc[ni][r] + bv;
                h[idx] = nh;
                h_bf_out[idx] = f2bf(nh);
            }
        }
    }
}

// ---------------------------------------------------------------------------
// fp32 tiled GEMM for K=32 encoders (verified core).
// OUT2: also write bf16. ECL: scatter into EC2 fragment layout.
// ---------------------------------------------------------------------------
template<int TM, bool OUTBF, bool OUT2, bool ECL>
__global__ __launch_bounds__(256) void gemm2(
    const float* __restrict__ A, int lda, int K,
    const float* __restrict__ W, int ldw, const float* __restrict__ bias,
    float* __restrict__ C, ushort* __restrict__ Cb, int ldc)
{
    constexpr int BM = TM * 16;
    constexpr int AV = BM / 64;
    __shared__ float As[16][BM + 4];
    __shared__ float Bs[16][132];
    const int tid = threadIdx.x;
    const int m0 = blockIdx.x * BM;
    const int n0 = blockIdx.y * 128;
    const int tx = tid & 15, ty = tid >> 4;
    const int arow = (AV == 2) ? (tid >> 1) : (tid >> 2);
    const int a0   = (AV == 2) ? ((tid & 1) * 8) : ((tid & 3) * 4);
    const int brow = ty;
    const int bcol = tx * 8;
    const int nch = K >> 4;

    float4 aC[AV], bC[2], aN[AV], bN[2];
    float acc[TM][8];
#pragma unroll
    for (int i = 0; i < TM; ++i)
#pragma unroll
        for (int j = 0; j < 8; ++j) acc[i][j] = 0.f;

    {
        const float* src = A + (size_t)(m0 + arow) * lda + a0;
        aC[0] = *(const float4*)src;
        if (AV == 2) aC[1] = *(const float4*)(src + 4);
        const float* bsrc = W + (size_t)brow * ldw + n0 + bcol;
        bC[0] = *(const float4*)bsrc;
        bC[1] = *(const float4*)(bsrc + 4);
    }

    for (int ch = 0; ch < nch; ++ch) {
        {
            const float* f = (const float*)aC;
#pragma unroll
            for (int i = 0; i < AV * 4; ++i) As[a0 + i][arow] = f[i];
            *(float4*)&Bs[brow][bcol]     = bC[0];
            *(float4*)&Bs[brow][bcol + 4] = bC[1];
        }
        __syncthreads();
        if (ch + 1 < nch) {
            const int kc = (ch + 1) << 4;
            const float* src = A + (size_t)(m0 + arow) * lda + kc + a0;
            aN[0] = *(const float4*)src;
            if (AV == 2) aN[1] = *(const float4*)(src + 4);
            const float* bsrc = W + (size_t)(kc + brow) * ldw + n0 + bcol;
            bN[0] = *(const float4*)bsrc;
            bN[1] = *(const float4*)(bsrc + 4);
        }
#pragma unroll
        for (int kk = 0; kk < 16; ++kk) {
            float afr[TM], bfr[8];
#pragma unroll
            for (int i = 0; i < TM; i += 4)
                *(float4*)&afr[i] = *(const float4*)&As[kk][ty * TM + i];
            *(float4*)&bfr[0] = *(const float4*)&Bs[kk][tx * 8];
            *(float4*)&bfr[4] = *(const float4*)&Bs[kk][tx * 8 + 4];
#pragma unroll
            for (int i = 0; i < TM; ++i)
#pragma unroll
                for (int j = 0; j < 8; ++j) acc[i][j] = fmaf(afr[i], bfr[j], acc[i][j]);
        }
        __syncthreads();
#pragma unroll
        for (int i = 0; i < AV; ++i) aC[i] = aN[i];
        bC[0] = bN[0]; bC[1] = bN[1];
    }
#pragma unroll
    for (int i = 0; i < TM; ++i) {
        const int row = m0 + ty * TM + i;
#pragma unroll
        for (int j = 0; j < 8; ++j) {
            const int col = n0 + tx * 8 + j;
            float v = acc[i][j] + bias[col];
            if (ECL) {
                const int gg = row >> 6, eloc = row & 63;
                const int p = col >> 8, kb = (col >> 5) & 7, jj = col & 31;
                Cb[(size_t)(((gg * 2 + p) * 8 + kb)) * 2048 + eloc * 32 + jj] = f2bf(v);
            } else if (OUTBF) {
                Cb[(size_t)row * ldc + col] = f2bf(v);
            } else {
                C[(size_t)row * ldc + col] = v;
                if (OUT2) Cb[(size_t)row * ldc + col] = f2bf(v);
            }
        }
    }
}

// ---------------------------------------------------------------------------
// Weight packing (verified)
// ---------------------------------------------------------------------------
__global__ __launch_bounds__(256) void pack2(
    const float* __restrict__ msg_w1, const float* __restrict__ rmsg_w1,
    const float* __restrict__ msg_b1, const float* __restrict__ rmsg_b1,
    const float* __restrict__ enc_ew, const float* __restrict__ enc_eb,
    const float* __restrict__ msg_w2, const float* __restrict__ rmsg_w2,
    const float* __restrict__ upd_w1, const float* __restrict__ upd_w2,
    float* __restrict__ Wcomb, float* __restrict__ bcomb,
    ushort* __restrict__ WhpL, ushort* __restrict__ W2fL, ushort* __restrict__ W2rL,
    ushort* __restrict__ UW1T, ushort* __restrict__ UW2T)
{
    const int gid = blockIdx.x, tid = threadIdx.x;
    if (gid < 64) {
        const int idx = gid * 256 + tid;
        const int a = idx >> 9, n = idx & 511;
        const float* Wsrc = (n < 256) ? msg_w1 : rmsg_w1;
        const int nc = n & 255;
        float s = 0.f;
        for (int j = 0; j < 128; ++j)
            s = fmaf(enc_ew[a * 128 + j], Wsrc[(256 + j) * 256 + nc], s);
        Wcomb[idx] = s;
    } else if (gid < 66) {
        const int n = (gid - 64) * 256 + tid;
        const float* Wsrc = (n < 256) ? msg_w1 : rmsg_w1;
        const float* bsrc = (n < 256) ? msg_b1 : rmsg_b1;
        const int nc = n & 255;
        float s = bsrc[nc];
        for (int j = 0; j < 128; ++j)
            s = fmaf(enc_eb[j], Wsrc[(256 + j) * 256 + nc], s);
        bcomb[n] = s;
    } else if (gid < 578) {
        const int idx = (gid - 66) * 256 + tid;        // [0,131072)
        const int n = idx >> 7, k = idx & 127;
        const float* Wsrc = (n < 512) ? msg_w1 : rmsg_w1;
        const int part = (n >> 8) & 1, col = n & 255;
        WhpL[(size_t)(k >> 5) * 32768 + n * 32 + (k & 31)] =
            f2bf(Wsrc[(part * 128 + k) * 256 + col]);
    } else if (gid < 706) {
        const int idx = (gid - 578) * 256 + tid;       // [0,32768)
        const int n = idx >> 8, k = idx & 255;
        W2fL[(size_t)(k >> 5) * 4096 + n * 32 + (k & 31)] = f2bf(msg_w2[k * 128 + n]);
    } else if (gid < 834) {
        const int idx = (gid - 706) * 256 + tid;
        const int n = idx >> 8, k = idx & 255;
        W2rL[(size_t)(k >> 5) * 4096 + n * 32 + (k & 31)] = f2bf(rmsg_w2[k * 128 + n]);
    } else if (gid < 1090) {
        const int idx = (gid - 834) * 256 + tid;
        const int n = idx >> 8, k = idx & 255;
        UW1T[idx] = f2bf(upd_w1[k * 256 + n]);
    } else {
        const int idx = (gid - 1090) * 256 + tid;
        const int n = idx >> 8, k = idx & 255;
        UW2T[idx] = f2bf(upd_w2[k * 128 + n]);
    }
}

// ---------------------------------------------------------------------------
// Node head (verified)
// ---------------------------------------------------------------------------
__global__ __launch_bounds__(256) void node_kernel(
    const float* __restrict__ h,
    const float* __restrict__ w1, const float* __restrict__ b1,
    const float* __restrict__ w2, const float* __restrict__ b2,
    const int* __restrict__ qsz, const int* __restrict__ csz,
    float* __restrict__ plan_out, float* __restrict__ loss_out)
{
    __shared__ float qn[32][128];
    __shared__ float cn[32][128];
    __shared__ float t1[32][64];
    __shared__ float mq[32][68];
    __shared__ float mc[32][68];
    __shared__ float la[32][33];
    __shared__ float red[4];
    const int bb = blockIdx.x;
    const int tid = threadIdx.x;
    const int qs = qsz[bb], cs = csz[bb];
    for (int u = tid * 4; u < 4096; u += 1024) {
        const int p = u >> 7, d = u & 127;
        float4 zq = make_float4(0.f, 0.f, 0.f, 0.f), zc = zq;
        if (p < NPG) {
            zq = *(const float4*)(h + (size_t)((2 * bb) * NPG + p) * 128 + d);
            zc = *(const float4*)(h + (size_t)((2 * bb + 1) * NPG + p) * 128 + d);
        }
        *(float4*)&qn[p][d] = zq;
        *(float4*)&cn[p][d] = zc;
    }
    __syncthreads();
    const int col = tid & 63;
    const int rg  = tid >> 6;
    for (int s = 0; s < 2; ++s) {
        const float (*src)[128] = s ? cn : qn;
        float (*dst)[68] = s ? mc : mq;
        const int sz = s ? cs : qs;
        float a8[8];
#pragma unroll
        for (int u = 0; u < 8; ++u) a8[u] = b1[col];
        for (int k = 0; k < 128; ++k) {
            const float wv = w1[k * 64 + col];
#pragma unroll
            for (int u = 0; u < 8; ++u) a8[u] = fmaf(src[rg + 4 * u][k], wv, a8[u]);
        }
#pragma unroll
        for (int u = 0; u < 8; ++u) t1[rg + 4 * u][col] = fmaxf(a8[u], 0.f);
        __syncthreads();
#pragma unroll
        for (int u = 0; u < 8; ++u) a8[u] = b2[col];
        for (int k = 0; k < 64; ++k) {
            const float wv = w2[k * 64 + col];
#pragma unroll
            for (int u = 0; u < 8; ++u) a8[u] = fmaf(t1[rg + 4 * u][k], wv, a8[u]);
        }
#pragma unroll
        for (int u = 0; u < 8; ++u) {
            const int r = rg + 4 * u;
            dst[r][col] = (r < sz) ? a8[u] : 0.f;
        }
        __syncthreads();
    }
    {
        const int q = tid >> 3, cg = tid & 7;
#pragma unroll
        for (int u = 0; u < 4; ++u) {
            const int c = cg + 8 * u;
            float s = 0.f;
            for (int d = 0; d < 64; ++d) s = fmaf(mq[q][d], mc[c][d], s);
            la[q][c] = s * TEMPINV;
        }
    }
    __syncthreads();
    const int l8 = tid & 7, rq = tid >> 3;
    for (int it = 0; it < SINK_ITERS; ++it) {
        {
            float x[4];
#pragma unroll
            for (int u = 0; u < 4; ++u) x[u] = la[rq][l8 * 4 + u];
            float m = fmaxf(fmaxf(x[0], x[1]), fmaxf(x[2], x[3]));
            m = fmaxf(m, __shfl_xor(m, 1));
            m = fmaxf(m, __shfl_xor(m, 2));
            m = fmaxf(m, __shfl_xor(m, 4));
            float s = __expf(x[0] - m) + __expf(x[1] - m) + __expf(x[2] - m) + __expf(x[3] - m);
            s += __shfl_xor(s, 1);
            s += __shfl_xor(s, 2);
            s += __shfl_xor(s, 4);
            const float lse = m + __logf(s);
#pragma unroll
            for (int u = 0; u < 4; ++u) la[rq][l8 * 4 + u] = x[u] - lse;
        }
        __syncthreads();
        {
            float x[4];
#pragma unroll
            for (int u = 0; u < 4; ++u) x[u] = la[l8 * 4 + u][rq];
            float m = fmaxf(fmaxf(x[0], x[1]), fmaxf(x[2], x[3]));
            m = fmaxf(m, __shfl_xor(m, 1));
            m = fmaxf(m, __shfl_xor(m, 2));
            m = fmaxf(m, __shfl_xor(m, 4));
            float s = __expf(x[0] - m) + __expf(x[1] - m) + __expf(x[2] - m) + __expf(x[3] - m);
            s += __shfl_xor(s, 1);
            s += __shfl_xor(s, 2);
            s += __shfl_xor(s, 4);
            const float lse = m + __logf(s);
#pragma unroll
            for (int u = 0; u < 4; ++u) la[l8 * 4 + u][rq] = x[u] - lse;
        }
        __syncthreads();
    }
    for (int u = tid; u < 1024; u += 256) {
        const int q = u >> 5, c = u & 31;
        const float p = __expf(la[q][c]);
        la[q][c] = p;
        plan_out[(size_t)bb * 1024 + u] = p;
    }
    __syncthreads();
    float lsum = 0.f;
    {
        const int q = tid >> 3, dg = tid & 7;
        for (int u = 0; u < 16; ++u) {
            const int d = dg + 8 * u;
            float pc = 0.f;
#pragma unroll
            for (int c = 0; c < 32; ++c) pc = fmaf(la[q][c], cn[c][d], pc);
            lsum += fmaxf(qn[q][d] - pc, 0.f);
        }
    }
#pragma unroll
    for (int off = 1; off < 64; off <<= 1) lsum += __shfl_xor(lsum, off);
    if ((tid & 63) == 0) red[tid >> 6] = lsum;
    __syncthreads();
    if (tid == 0) loss_out[bb] = -(red[0] + red[1] + red[2] + red[3]);
}

// ---------------------------------------------------------------------------
// Edge head — EM = EMF + EMR summed on load
// ---------------------------------------------------------------------------
__global__ __launch_bounds__(256) void edge_kernel(
    const float* __restrict__ plan,
    const float* __restrict__ EMF, const float* __restrict__ EMR,
    const int* __restrict__ from_idx, const int* __restrict__ to_idx,
    float* __restrict__ loss_out)
{
    __shared__ float T[32][33];
    __shared__ float la[64][65];
    __shared__ float ce[64][128];
    __shared__ int qf[64], qt[64], cfi[64], cti[64];
    __shared__ float red[4];
    const int bb = blockIdx.x;
    const int tid = threadIdx.x;
    for (int u = tid; u < 1024; u += 256) T[u >> 5][u & 31] = plan[(size_t)bb * 1024 + u];
    if (tid < 64) {
        const int gq = 2 * bb, gc = 2 * bb + 1;
        qf[tid]  = from_idx[gq * 64 + tid] - gq * NPG;
        qt[tid]  = to_idx  [gq * 64 + tid] - gq * NPG;
        cfi[tid] = from_idx[gc * 64 + tid] - gc * NPG;
        cti[tid] = to_idx  [gc * 64 + tid] - gc * NPG;
    }
    {
        const int gc = 2 * bb + 1;
        for (int u = tid * 4; u < 8192; u += 1024) {
            const int i = u >> 7, d = u & 127;
            const size_t idx = (size_t)(gc * 64 + i) * 128 + d;
            const float4 vf = *(const float4*)(EMF + idx);
            const float4 vr = *(const float4*)(EMR + idx);
            float4 v;
            v.x = vf.x + vr.x; v.y = vf.y + vr.y;
            v.z = vf.z + vr.z; v.w = vf.w + vr.w;
            *(float4*)&ce[i][d] = v;
        }
    }
    __syncthreads();
    {
        const int i = tid >> 2, jg = tid & 3;
        const int a = qf[i], b_ = qt[i];
#pragma unroll
        for (int u = 0; u < 16; ++u) {
            const int j = jg * 16 + u;
            const float s = T[a][cfi[j]] * T[b_][cti[j]] + T[a][cti[j]] * T[b_][cfi[j]];
            la[i][j] = s * TEMPINV;
        }
    }
    __syncthreads();
    const int l4 = tid & 3, rr = tid >> 2;
    for (int it = 0; it < SINK_ITERS; ++it) {
        {
            float x[16];
#pragma unroll
            for (int u = 0; u < 16; ++u) x[u] = la[rr][l4 * 16 + u];
            float m = x[0];
#pragma unroll
            for (int u = 1; u < 16; ++u) m = fmaxf(m, x[u]);
            m = fmaxf(m, __shfl_xor(m, 1));
            m = fmaxf(m, __shfl_xor(m, 2));
            float s = 0.f;
#pragma unroll
            for (int u = 0; u < 16; ++u) s += __expf(x[u] - m);
            s += __shfl_xor(s, 1);
            s += __shfl_xor(s, 2);
            const float lse = m + __logf(s);
#pragma unroll
            for (int u = 0; u < 16; ++u) la[rr][l4 * 16 + u] = x[u] - lse;
        }
        __syncthreads();
        {
            float x[16];
#pragma unroll
            for (int u = 0; u < 16; ++u) x[u] = la[l4 * 16 + u][rr];
            float m = x[0];
#pragma unroll
            for (int u = 1; u < 16; ++u) m = fmaxf(m, x[u]);
            m = fmaxf(m, __shfl_xor(m, 1));
            m = fmaxf(m, __shfl_xor(m, 2));
            float s = 0.f;
#pragma unroll
            for (int u = 0; u < 16; ++u) s += __expf(x[u] - m);
            s += __shfl_xor(s, 1);
            s += __shfl_xor(s, 2);
            const float lse = m + __logf(s);
#pragma unroll
            for (int u = 0; u < 16; ++u) la[l4 * 16 + u][rr] = x[u] - lse;
        }
        __syncthreads();
    }
    for (int u = tid; u < 4096; u += 256) la[u >> 6][u & 63] = __expf(la[u >> 6][u & 63]);
    __syncthreads();
    float lsum = 0.f;
    {
        const int q = tid >> 2, dg = tid & 3;
        const size_t qbase = (size_t)((2 * bb) * 64 + q) * 128;
        for (int u = 0; u < 32; ++u) {
            const int d = dg + 4 * u;
            float pc = 0.f;
            for (int c = 0; c < 64; ++c) pc = fmaf(la[q][c], ce[c][d], pc);
            const float qe = EMF[qbase + d] + EMR[qbase + d];
            lsum += fmaxf(qe - pc, 0.f);
        }
    }
#pragma unroll
    for (int off = 1; off < 64; off <<= 1) lsum += __shfl_xor(lsum, off);
    if ((tid & 63) == 0) red[tid >> 6] = lsum;
    __syncthreads();
    if (tid == 0) loss_out[bb] -= CW * (red[0] + red[1] + red[2] + red[3]);
}

// ---------------------------------------------------------------------------
extern "C" void kernel_launch(void* const* d_in, const int* in_sizes, int n_in,
                              void* d_out, int out_size, void* d_ws, size_t ws_size,
                              hipStream_t stream)
{
    const float* node_features = (const float*)d_in[0];
    const float* edge_features = (const float*)d_in[1];
    const float* enc_nw  = (const float*)d_in[2];
    const float* enc_nb  = (const float*)d_in[3];
    const float* enc_ew  = (const float*)d_in[4];
    const float* enc_eb  = (const float*)d_in[5];
    const float* msg_w1  = (const float*)d_in[6];
    const float* msg_b1  = (const float*)d_in[7];
    const float* msg_w2  = (const float*)d_in[8];
    const float* msg_b2  = (const float*)d_in[9];
    const float* rmsg_w1 = (const float*)d_in[10];
    const float* rmsg_b1 = (const float*)d_in[11];
    const float* rmsg_w2 = (const float*)d_in[12];
    const float* rmsg_b2 = (const float*)d_in[13];
    const float* upd_w1  = (const float*)d_in[14];
    const float* upd_b1  = (const float*)d_in[15];
    const float* upd_w2  = (const float*)d_in[16];
    const float* upd_b2  = (const float*)d_in[17];
    const float* sk_w1   = (const float*)d_in[18];
    const float* sk_b1   = (const float*)d_in[19];
    const float* sk_w2   = (const float*)d_in[20];
    const float* sk_b2   = (const float*)d_in[21];
    const int* from_idx  = (const int*)d_in[22];
    const int* to_idx    = (const int*)d_in[23];
    const int* qsizes    = (const int*)d_in[24];
    const int* csizes    = (const int*)d_in[25];
    float* out = (float*)d_out;

    float* ws    = (float*)d_ws;
    float* h     = ws;                          // NN*128 fp32
    float* EMF   = h + (size_t)NN * 128;        // NE*128 fp32
    float* EMR   = EMF + (size_t)NE * 128;      // NE*128 fp32
    float* plan  = EMR + (size_t)NE * 128;      // NB*1024
    float* Wcomb = plan + (size_t)NB * 1024;    // 32*512
    float* bcomb = Wcomb + 16384;               // 512
    ushort* h_bf = (ushort*)(bcomb + 512);      // NN*128
    ushort* EC2  = h_bf + (size_t)NN * 128;     // NE*512
    ushort* aggF = EC2 + (size_t)NE * 512;      // NN*128
    ushort* aggR = aggF + (size_t)NN * 128;     // NN*128
    ushort* WhpL = aggR + (size_t)NN * 128;     // 131072
    ushort* W2fL = WhpL + 131072;               // 32768
    ushort* W2rL = W2fL + 32768;                // 32768
    ushort* UW1T = W2rL + 32768;                // 65536
    ushort* UW2T = UW1T + 65536;                // 32768

    const dim3 blk(256);

    pack2<<<1218, blk, 0, stream>>>(msg_w1, rmsg_w1, msg_b1, rmsg_b1,
                                    enc_ew, enc_eb, msg_w2, rmsg_w2, upd_w1, upd_w2,
                                    Wcomb, bcomb, WhpL, W2fL, W2rL, UW1T, UW2T);
    // node encoder: h (fp32) + h_bf
    gemm2<4, false, true, false><<<dim3(NN / 64, 1), blk, 0, stream>>>(
        node_features, 32, 32, enc_nw, 128, enc_nb, h, h_bf, 128);
    // edge encoder folded with msg layer-1 edge slice -> EC2 fragment layout
    gemm2<8, false, false, true><<<dim3(NE / 128, 4), blk, 0, stream>>>(
        edge_features, 32, 32, Wcomb, 512, bcomb, nullptr, EC2, 512);

    for (int step = 0; step < 3; ++step) {
        msg_fused<true><<<dim3(NG, 2), blk, 0, stream>>>(
            h_bf, EC2, WhpL, W2fL, W2rL, msg_b2, rmsg_b2, from_idx, to_idx,
            aggF, aggR, nullptr, nullptr);
        upd_fused<<<dim3(NN / 16), blk, 0, stream>>>(
            aggF, aggR, h_bf, UW1T, upd_b1, UW2T, upd_b2, h, h_bf);
    }

    msg_fused<false><<<dim3(NG, 2), blk, 0, stream>>>(
        h_bf, EC2, WhpL, W2fL, W2rL, msg_b2, rmsg_b2, from_idx, to_idx,
        nullptr, nullptr, EMF, EMR);

    node_kernel<<<NB, blk, 0, stream>>>(
        h, sk_w1, sk_b1, sk_w2, sk_b2, qsizes, csizes, plan, out);
    edge_kernel<<<NB, blk, 0, stream>>>(
        plan, EMF, EMR, from_idx, to_idx, out);
}

// Round 9
// 594.094 us; speedup vs baseline: 1.0396x; 1.0396x over previous
//
#include <hip/hip_runtime.h>
#include <math.h>

#define NPG 28
#define EPG 64
#define NB  256
#define NG  512
#define NN  14336
#define NE  32768
#define TEMPINV 10.0f
#define SINK_ITERS 20
#define CW 0.9f

typedef unsigned int uint;
typedef unsigned short ushort;
typedef __attribute__((ext_vector_type(8))) __bf16 bf16x8;
typedef __attribute__((ext_vector_type(4))) float f32x4;

__device__ __forceinline__ ushort f2bf(float x) {
    uint u = __float_as_uint(x);
    u += 0x7fffu + ((u >> 16) & 1u);
    return (ushort)(u >> 16);
}
__device__ __forceinline__ float bflo(uint w) { return __uint_as_float(w << 16); }
__device__ __forceinline__ float bfhi(uint w) { return __uint_as_float(w & 0xffff0000u); }
__device__ __forceinline__ uint relu_sum_pk(uint w1, uint w2, uint w3) {
    float lo = fmaxf(bflo(w1) + bflo(w2) + bflo(w3), 0.f);
    float hi = fmaxf(bfhi(w1) + bfhi(w2) + bfhi(w3), 0.f);
    return (uint)f2bf(lo) | ((uint)f2bf(hi) << 16);
}
__device__ __forceinline__ f32x4 mfma16(bf16x8 a, bf16x8 b, f32x4 c) {
    return __builtin_amdgcn_mfma_f32_16x16x32_bf16(a, b, c, 0, 0, 0);
}

// ---------------------------------------------------------------------------
// Fused message kernel v5: one block = one graph, 512 threads (8 waves).
// Per pass p: HP pass-half = h@Whp via MFMA into LDS (wave w -> 64 cols),
// then layer-2 GEMM: wave (wm=w>>1, wn=w&1) -> edges [wm*16,+16) x cols
// [wn*64,+64); A repacked from LDS HP gathers + coalesced EC2; each wave
// repacks only its own 16 edges. SEG: LDS atomic segment-sum -> agg bf16.
// EMIT: acc shared across passes -> EM fp32 (+b2f+b2r).
// LDS: HPs 29.1KB + acc_s 14.3KB (SEG) + idx 0.5KB = 44KB.
// ---------------------------------------------------------------------------
template<bool SEG>
__global__ __launch_bounds__(512, 4) void msg_fused(
    const ushort* __restrict__ h_bf, const ushort* __restrict__ EC2,
    const ushort* __restrict__ WhpL,
    const ushort* __restrict__ W2fL, const ushort* __restrict__ W2rL,
    const float* __restrict__ b2f, const float* __restrict__ b2r,
    const int* __restrict__ from_idx, const int* __restrict__ to_idx,
    ushort* __restrict__ agg, float* __restrict__ EM)
{
    __shared__ ushort HPs[NPG * 520];        // 28 x 512 pass-half, stride 520
    __shared__ float acc_s[SEG ? NPG * 128 : 64];
    __shared__ int fl[64], tl[64];
    const int g = blockIdx.x;
    const int tid = threadIdx.x;
    const int w = tid >> 6, lane = tid & 63;
    const int li = lane & 15, quad = lane >> 4;
    const int wm = w >> 1, wn = w & 1;
    const int n0 = wn * 64;

    if (tid < 64) {
        fl[tid] = from_idx[g * 64 + tid] - g * NPG;
        tl[tid] = to_idx[g * 64 + tid] - g * NPG;
    }
    if (SEG) {
        for (int u = tid; u < NPG * 128; u += 512) acc_s[u] = 0.f;
    }

    // h A-frags (rows 0..27, guarded pad) straight from global (L2-resident)
    uint4 ha[2][4];
#pragma unroll
    for (int mi = 0; mi < 2; ++mi) {
        const int row = mi * 16 + li;
        const int rr = (row < NPG) ? row : 0;
        const ushort* src = h_bf + ((size_t)g * NPG + rr) * 128 + quad * 8;
#pragma unroll
        for (int kb = 0; kb < 4; ++kb) ha[mi][kb] = *(const uint4*)(src + kb * 32);
    }

    f32x4 acc[4];
#pragma unroll
    for (int j = 0; j < 4; ++j) acc[j] = f32x4{0.f, 0.f, 0.f, 0.f};

    for (int p = 0; p < 2; ++p) {
        {   // ---- HP pass-half: wave w -> local cols [w*64, w*64+64)
            const int colw = w * 64;
#pragma unroll
            for (int ni = 0; ni < 4; ++ni) {
                const int col = colw + ni * 16 + li;       // [0,512)
                const ushort* pb = WhpL + (size_t)(p * 512 + col) * 32 + quad * 8;
                f32x4 c0 = f32x4{0.f, 0.f, 0.f, 0.f};
                f32x4 c1 = f32x4{0.f, 0.f, 0.f, 0.f};
#pragma unroll
                for (int kb = 0; kb < 4; ++kb) {
                    const bf16x8 b = __builtin_bit_cast(bf16x8,
                        *(const uint4*)(pb + (size_t)kb * 32768));
                    c0 = mfma16(__builtin_bit_cast(bf16x8, ha[0][kb]), b, c0);
                    c1 = mfma16(__builtin_bit_cast(bf16x8, ha[1][kb]), b, c1);
                }
#pragma unroll
                for (int r = 0; r < 4; ++r) {
                    const int r0 = quad * 4 + r;
                    HPs[r0 * 520 + col] = f2bf(c0[r]);
                    const int r1 = 16 + quad * 4 + r;
                    if (r1 < NPG) HPs[r1 * 520 + col] = f2bf(c1[r]);
                }
            }
        }
        __syncthreads();   // HPs ready (also covers acc_s zero / fl,tl on p=0)

        if (SEG && p == 1) {
#pragma unroll
            for (int j = 0; j < 4; ++j) acc[j] = f32x4{0.f, 0.f, 0.f, 0.f};
        }

        // ---- layer-2: wave (wm,wn): edges [wm*16,+16), cols [wn*64,+64)
        const int e = wm * 16 + li;
        const int i1 = p ? tl[e] : fl[e];
        const int i2 = p ? fl[e] : tl[e];
        const int ad1 = i1 * 520 + quad * 8;
        const int ad2 = i2 * 520 + 256 + quad * 8;
        const int ade = e * 32 + quad * 8;
        const ushort* ecb = EC2 + (size_t)(g * 2 + p) * 16384;
        const ushort* W2L = p ? W2rL : W2fL;
        const ushort* pb[4];
#pragma unroll
        for (int ni = 0; ni < 4; ++ni)
            pb[ni] = W2L + (size_t)(n0 + ni * 16 + li) * 32 + quad * 8;
#pragma unroll
        for (int kb = 0; kb < 8; ++kb) {
            const uint4 u1 = *(const uint4*)&HPs[ad1 + kb * 32];
            const uint4 u2 = *(const uint4*)&HPs[ad2 + kb * 32];
            const uint4 ue = *(const uint4*)(ecb + kb * 2048 + ade);
            uint4 o;
            o.x = relu_sum_pk(u1.x, u2.x, ue.x);
            o.y = relu_sum_pk(u1.y, u2.y, ue.y);
            o.z = relu_sum_pk(u1.z, u2.z, ue.z);
            o.w = relu_sum_pk(u1.w, u2.w, ue.w);
            const bf16x8 a = __builtin_bit_cast(bf16x8, o);
#pragma unroll
            for (int ni = 0; ni < 4; ++ni) {
                const bf16x8 b = __builtin_bit_cast(bf16x8,
                    *(const uint4*)(pb[ni] + (size_t)kb * 4096));
                acc[ni] = mfma16(a, b, acc[ni]);
            }
        }

        if (SEG) {
            const int* targ = p ? fl : tl;
            const float* bias = p ? b2r : b2f;
            float bv[4];
#pragma unroll
            for (int ni = 0; ni < 4; ++ni) bv[ni] = bias[n0 + ni * 16 + li];
#pragma unroll
            for (int r = 0; r < 4; ++r) {
                const int loc = targ[wm * 16 + quad * 4 + r];
#pragma unroll
                for (int ni = 0; ni < 4; ++ni)
                    atomicAdd(&acc_s[loc * 128 + n0 + ni * 16 + li],
                              acc[ni][r] + bv[ni]);
            }
        }
        __syncthreads();   // atomics drained / HPs reusable
    }

    if (SEG) {
        ushort* dst = agg + (size_t)g * (NPG * 128);
        for (int u = tid; u < NPG * 128; u += 512) dst[u] = f2bf(acc_s[u]);
    } else {
        float bv[4];
#pragma unroll
        for (int ni = 0; ni < 4; ++ni)
            bv[ni] = b2f[n0 + ni * 16 + li] + b2r[n0 + ni * 16 + li];
#pragma unroll
        for (int r = 0; r < 4; ++r) {
            const int erow = g * 64 + wm * 16 + quad * 4 + r;
#pragma unroll
            for (int ni = 0; ni < 4; ++ni)
                EM[(size_t)erow * 128 + n0 + ni * 16 + li] = acc[ni][r] + bv[ni];
        }
    }
}

// ---------------------------------------------------------------------------
// Fused update MLP (verified round-6 core): 16-row tiles, single agg.
// ---------------------------------------------------------------------------
__global__ __launch_bounds__(256) void upd_fused(
    const ushort* __restrict__ agg, const ushort* __restrict__ hbf,
    const ushort* __restrict__ UW1T, const float* __restrict__ b1,
    const ushort* __restrict__ UW2T, const float* __restrict__ b2,
    float* __restrict__ h, ushort* __restrict__ h_bf_out)
{
    __shared__ ushort hid_s[16][264];
    const int tid = threadIdx.x;
    const int w = tid >> 6, lane = tid & 63;
    const int li = lane & 15, quad = lane >> 4;
    const int m0 = blockIdx.x * 16;

    {   // phase 1
        const int n0 = w * 64;
        f32x4 acc[4];
#pragma unroll
        for (int j = 0; j < 4; ++j) acc[j] = f32x4{0.f, 0.f, 0.f, 0.f};
        const ushort* pb[4];
#pragma unroll
        for (int ni = 0; ni < 4; ++ni)
            pb[ni] = UW1T + (size_t)(n0 + ni * 16 + li) * 256 + quad * 8;
        const ushort* pa_a = agg + (size_t)(m0 + li) * 128 + quad * 8;
        const ushort* pa_h = hbf + (size_t)(m0 + li) * 128 + quad * 8;
#pragma unroll
        for (int kb = 0; kb < 8; ++kb) {
            const ushort* src = (kb < 4) ? (pa_a + kb * 32) : (pa_h + (kb - 4) * 32);
            const bf16x8 a = __builtin_bit_cast(bf16x8, *(const uint4*)src);
            bf16x8 b[4];
#pragma unroll
            for (int ni = 0; ni < 4; ++ni)
                b[ni] = __builtin_bit_cast(bf16x8, *(const uint4*)(pb[ni] + kb * 32));
#pragma unroll
            for (int ni = 0; ni < 4; ++ni) acc[ni] = mfma16(a, b[ni], acc[ni]);
        }
#pragma unroll
        for (int ni = 0; ni < 4; ++ni) {
            const float bv = b1[n0 + ni * 16 + li];
#pragma unroll
            for (int r = 0; r < 4; ++r)
                hid_s[quad * 4 + r][n0 + ni * 16 + li] =
                    f2bf(fmaxf(acc[ni][r] + bv, 0.f));
        }
    }
    __syncthreads();
    {   // phase 2
        const int n0 = w * 32;
        f32x4 acc[2];
#pragma unroll
        for (int j = 0; j < 2; ++j) acc[j] = f32x4{0.f, 0.f, 0.f, 0.f};
        const ushort* pb[2];
#pragma unroll
        for (int ni = 0; ni < 2; ++ni)
            pb[ni] = UW2T + (size_t)(n0 + ni * 16 + li) * 256 + quad * 8;
#pragma unroll
        for (int kb = 0; kb < 8; ++kb) {
            const bf16x8 a = __builtin_bit_cast(bf16x8,
                *(const uint4*)&hid_s[li][kb * 32 + quad * 8]);
            bf16x8 b[2];
#pragma unroll
            for (int ni = 0; ni < 2; ++ni)
                b[ni] = __builtin_bit_cast(bf16x8, *(const uint4*)(pb[ni] + kb * 32));
#pragma unroll
            for (int ni = 0; ni < 2; ++ni) acc[ni] = mfma16(a, b[ni], acc[ni]);
        }
#pragma unroll
        for (int ni = 0; ni < 2; ++ni) {
            const int ncol = n0 + ni * 16 + li;
            const float bv = b2[ncol];
#pragma unroll
            for (int r = 0; r < 4; ++r) {
                const int row = m0 + quad * 4 + r;
                const size_t idx = (size_t)row * 128 + ncol;
                const float nh = h[idx] + acc[ni][r] + bv;
                h[idx] = nh;
                h_bf_out[idx] = f2bf(nh);
            }
        }
    }
}

// ---------------------------------------------------------------------------
// fp32 tiled GEMM for K=32 encoders (verified core).
// OUT2: also write bf16. ECL: scatter into EC2 fragment layout.
// ---------------------------------------------------------------------------
template<int TM, bool OUTBF, bool OUT2, bool ECL>
__global__ __launch_bounds__(256) void gemm2(
    const float* __restrict__ A, int lda, int K,
    const float* __restrict__ W, int ldw, const float* __restrict__ bias,
    float* __restrict__ C, ushort* __restrict__ Cb, int ldc)
{
    constexpr int BM = TM * 16;
    constexpr int AV = BM / 64;
    __shared__ float As[16][BM + 4];
    __shared__ float Bs[16][132];
    const int tid = threadIdx.x;
    const int m0 = blockIdx.x * BM;
    const int n0 = blockIdx.y * 128;
    const int tx = tid & 15, ty = tid >> 4;
    const int arow = (AV == 2) ? (tid >> 1) : (tid >> 2);
    const int a0   = (AV == 2) ? ((tid & 1) * 8) : ((tid & 3) * 4);
    const int brow = ty;
    const int bcol = tx * 8;
    const int nch = K >> 4;

    float4 aC[2], bC[2], aN[2], bN[2];   // [2] always: avoids -Warray-bounds
    float acc[TM][8];
#pragma unroll
    for (int i = 0; i < TM; ++i)
#pragma unroll
        for (int j = 0; j < 8; ++j) acc[i][j] = 0.f;

    {
        const float* src = A + (size_t)(m0 + arow) * lda + a0;
        aC[0] = *(const float4*)src;
        if (AV == 2) aC[1] = *(const float4*)(src + 4);
        const float* bsrc = W + (size_t)brow * ldw + n0 + bcol;
        bC[0] = *(const float4*)bsrc;
        bC[1] = *(const float4*)(bsrc + 4);
    }

    for (int ch = 0; ch < nch; ++ch) {
        {
            const float* f = (const float*)aC;
#pragma unroll
            for (int i = 0; i < AV * 4; ++i) As[a0 + i][arow] = f[i];
            *(float4*)&Bs[brow][bcol]     = bC[0];
            *(float4*)&Bs[brow][bcol + 4] = bC[1];
        }
        __syncthreads();
        if (ch + 1 < nch) {
            const int kc = (ch + 1) << 4;
            const float* src = A + (size_t)(m0 + arow) * lda + kc + a0;
            aN[0] = *(const float4*)src;
            if (AV == 2) aN[1] = *(const float4*)(src + 4);
            const float* bsrc = W + (size_t)(kc + brow) * ldw + n0 + bcol;
            bN[0] = *(const float4*)bsrc;
            bN[1] = *(const float4*)(bsrc + 4);
        }
#pragma unroll
        for (int kk = 0; kk < 16; ++kk) {
            float afr[TM], bfr[8];
#pragma unroll
            for (int i = 0; i < TM; i += 4)
                *(float4*)&afr[i] = *(const float4*)&As[kk][ty * TM + i];
            *(float4*)&bfr[0] = *(const float4*)&Bs[kk][tx * 8];
            *(float4*)&bfr[4] = *(const float4*)&Bs[kk][tx * 8 + 4];
#pragma unroll
            for (int i = 0; i < TM; ++i)
#pragma unroll
                for (int j = 0; j < 8; ++j) acc[i][j] = fmaf(afr[i], bfr[j], acc[i][j]);
        }
        __syncthreads();
        aC[0] = aN[0]; aC[1] = aN[1];
        bC[0] = bN[0]; bC[1] = bN[1];
    }
#pragma unroll
    for (int i = 0; i < TM; ++i) {
        const int row = m0 + ty * TM + i;
#pragma unroll
        for (int j = 0; j < 8; ++j) {
            const int col = n0 + tx * 8 + j;
            float v = acc[i][j] + bias[col];
            if (ECL) {
                const int gg = row >> 6, eloc = row & 63;
                const int p = col >> 8, kb = (col >> 5) & 7, jj = col & 31;
                Cb[(size_t)(((gg * 2 + p) * 8 + kb)) * 2048 + eloc * 32 + jj] = f2bf(v);
            } else if (OUTBF) {
                Cb[(size_t)row * ldc + col] = f2bf(v);
            } else {
                C[(size_t)row * ldc + col] = v;
                if (OUT2) Cb[(size_t)row * ldc + col] = f2bf(v);
            }
        }
    }
}

// ---------------------------------------------------------------------------
// Weight packing (verified)
// ---------------------------------------------------------------------------
__global__ __launch_bounds__(256) void pack2(
    const float* __restrict__ msg_w1, const float* __restrict__ rmsg_w1,
    const float* __restrict__ msg_b1, const float* __restrict__ rmsg_b1,
    const float* __restrict__ enc_ew, const float* __restrict__ enc_eb,
    const float* __restrict__ msg_w2, const float* __restrict__ rmsg_w2,
    const float* __restrict__ upd_w1, const float* __restrict__ upd_w2,
    float* __restrict__ Wcomb, float* __restrict__ bcomb,
    ushort* __restrict__ WhpL, ushort* __restrict__ W2fL, ushort* __restrict__ W2rL,
    ushort* __restrict__ UW1T, ushort* __restrict__ UW2T)
{
    const int gid = blockIdx.x, tid = threadIdx.x;
    if (gid < 64) {
        const int idx = gid * 256 + tid;
        const int a = idx >> 9, n = idx & 511;
        const float* Wsrc = (n < 256) ? msg_w1 : rmsg_w1;
        const int nc = n & 255;
        float s = 0.f;
        for (int j = 0; j < 128; ++j)
            s = fmaf(enc_ew[a * 128 + j], Wsrc[(256 + j) * 256 + nc], s);
        Wcomb[idx] = s;
    } else if (gid < 66) {
        const int n = (gid - 64) * 256 + tid;
        const float* Wsrc = (n < 256) ? msg_w1 : rmsg_w1;
        const float* bsrc = (n < 256) ? msg_b1 : rmsg_b1;
        const int nc = n & 255;
        float s = bsrc[nc];
        for (int j = 0; j < 128; ++j)
            s = fmaf(enc_eb[j], Wsrc[(256 + j) * 256 + nc], s);
        bcomb[n] = s;
    } else if (gid < 578) {
        const int idx = (gid - 66) * 256 + tid;        // [0,131072)
        const int n = idx >> 7, k = idx & 127;
        const float* Wsrc = (n < 512) ? msg_w1 : rmsg_w1;
        const int part = (n >> 8) & 1, col = n & 255;
        WhpL[(size_t)(k >> 5) * 32768 + n * 32 + (k & 31)] =
            f2bf(Wsrc[(part * 128 + k) * 256 + col]);
    } else if (gid < 706) {
        const int idx = (gid - 578) * 256 + tid;       // [0,32768)
        const int n = idx >> 8, k = idx & 255;
        W2fL[(size_t)(k >> 5) * 4096 + n * 32 + (k & 31)] = f2bf(msg_w2[k * 128 + n]);
    } else if (gid < 834) {
        const int idx = (gid - 706) * 256 + tid;
        const int n = idx >> 8, k = idx & 255;
        W2rL[(size_t)(k >> 5) * 4096 + n * 32 + (k & 31)] = f2bf(rmsg_w2[k * 128 + n]);
    } else if (gid < 1090) {
        const int idx = (gid - 834) * 256 + tid;
        const int n = idx >> 8, k = idx & 255;
        UW1T[idx] = f2bf(upd_w1[k * 256 + n]);
    } else {
        const int idx = (gid - 1090) * 256 + tid;
        const int n = idx >> 8, k = idx & 255;
        UW2T[idx] = f2bf(upd_w2[k * 128 + n]);
    }
}

// ---------------------------------------------------------------------------
// Node head (verified)
// ---------------------------------------------------------------------------
__global__ __launch_bounds__(256) void node_kernel(
    const float* __restrict__ h,
    const float* __restrict__ w1, const float* __restrict__ b1,
    const float* __restrict__ w2, const float* __restrict__ b2,
    const int* __restrict__ qsz, const int* __restrict__ csz,
    float* __restrict__ plan_out, float* __restrict__ loss_out)
{
    __shared__ float qn[32][128];
    __shared__ float cn[32][128];
    __shared__ float t1[32][64];
    __shared__ float mq[32][68];
    __shared__ float mc[32][68];
    __shared__ float la[32][33];
    __shared__ float red[4];
    const int bb = blockIdx.x;
    const int tid = threadIdx.x;
    const int qs = qsz[bb], cs = csz[bb];
    for (int u = tid * 4; u < 4096; u += 1024) {
        const int p = u >> 7, d = u & 127;
        float4 zq = make_float4(0.f, 0.f, 0.f, 0.f), zc = zq;
        if (p < NPG) {
            zq = *(const float4*)(h + (size_t)((2 * bb) * NPG + p) * 128 + d);
            zc = *(const float4*)(h + (size_t)((2 * bb + 1) * NPG + p) * 128 + d);
        }
        *(float4*)&qn[p][d] = zq;
        *(float4*)&cn[p][d] = zc;
    }
    __syncthreads();
    const int col = tid & 63;
    const int rg  = tid >> 6;
    for (int s = 0; s < 2; ++s) {
        const float (*src)[128] = s ? cn : qn;
        float (*dst)[68] = s ? mc : mq;
        const int sz = s ? cs : qs;
        float a8[8];
#pragma unroll
        for (int u = 0; u < 8; ++u) a8[u] = b1[col];
        for (int k = 0; k < 128; ++k) {
            const float wv = w1[k * 64 + col];
#pragma unroll
            for (int u = 0; u < 8; ++u) a8[u] = fmaf(src[rg + 4 * u][k], wv, a8[u]);
        }
#pragma unroll
        for (int u = 0; u < 8; ++u) t1[rg + 4 * u][col] = fmaxf(a8[u], 0.f);
        __syncthreads();
#pragma unroll
        for (int u = 0; u < 8; ++u) a8[u] = b2[col];
        for (int k = 0; k < 64; ++k) {
            const float wv = w2[k * 64 + col];
#pragma unroll
            for (int u = 0; u < 8; ++u) a8[u] = fmaf(t1[rg + 4 * u][k], wv, a8[u]);
        }
#pragma unroll
        for (int u = 0; u < 8; ++u) {
            const int r = rg + 4 * u;
            dst[r][col] = (r < sz) ? a8[u] : 0.f;
        }
        __syncthreads();
    }
    {
        const int q = tid >> 3, cg = tid & 7;
#pragma unroll
        for (int u = 0; u < 4; ++u) {
            const int c = cg + 8 * u;
            float s = 0.f;
            for (int d = 0; d < 64; ++d) s = fmaf(mq[q][d], mc[c][d], s);
            la[q][c] = s * TEMPINV;
        }
    }
    __syncthreads();
    const int l8 = tid & 7, rq = tid >> 3;
    for (int it = 0; it < SINK_ITERS; ++it) {
        {
            float x[4];
#pragma unroll
            for (int u = 0; u < 4; ++u) x[u] = la[rq][l8 * 4 + u];
            float m = fmaxf(fmaxf(x[0], x[1]), fmaxf(x[2], x[3]));
            m = fmaxf(m, __shfl_xor(m, 1));
            m = fmaxf(m, __shfl_xor(m, 2));
            m = fmaxf(m, __shfl_xor(m, 4));
            float s = __expf(x[0] - m) + __expf(x[1] - m) + __expf(x[2] - m) + __expf(x[3] - m);
            s += __shfl_xor(s, 1);
            s += __shfl_xor(s, 2);
            s += __shfl_xor(s, 4);
            const float lse = m + __logf(s);
#pragma unroll
            for (int u = 0; u < 4; ++u) la[rq][l8 * 4 + u] = x[u] - lse;
        }
        __syncthreads();
        {
            float x[4];
#pragma unroll
            for (int u = 0; u < 4; ++u) x[u] = la[l8 * 4 + u][rq];
            float m = fmaxf(fmaxf(x[0], x[1]), fmaxf(x[2], x[3]));
            m = fmaxf(m, __shfl_xor(m, 1));
            m = fmaxf(m, __shfl_xor(m, 2));
            m = fmaxf(m, __shfl_xor(m, 4));
            float s = __expf(x[0] - m) + __expf(x[1] - m) + __expf(x[2] - m) + __expf(x[3] - m);
            s += __shfl_xor(s, 1);
            s += __shfl_xor(s, 2);
            s += __shfl_xor(s, 4);
            const float lse = m + __logf(s);
#pragma unroll
            for (int u = 0; u < 4; ++u) la[l8 * 4 + u][rq] = x[u] - lse;
        }
        __syncthreads();
    }
    for (int u = tid; u < 1024; u += 256) {
        const int q = u >> 5, c = u & 31;
        const float p = __expf(la[q][c]);
        la[q][c] = p;
        plan_out[(size_t)bb * 1024 + u] = p;
    }
    __syncthreads();
    float lsum = 0.f;
    {
        const int q = tid >> 3, dg = tid & 7;
        for (int u = 0; u < 16; ++u) {
            const int d = dg + 8 * u;
            float pc = 0.f;
#pragma unroll
            for (int c = 0; c < 32; ++c) pc = fmaf(la[q][c], cn[c][d], pc);
            lsum += fmaxf(qn[q][d] - pc, 0.f);
        }
    }
#pragma unroll
    for (int off = 1; off < 64; off <<= 1) lsum += __shfl_xor(lsum, off);
    if ((tid & 63) == 0) red[tid >> 6] = lsum;
    __syncthreads();
    if (tid == 0) loss_out[bb] = -(red[0] + red[1] + red[2] + red[3]);
}

// ---------------------------------------------------------------------------
// Edge head (verified round-6)
// ---------------------------------------------------------------------------
__global__ __launch_bounds__(256) void edge_kernel(
    const float* __restrict__ plan, const float* __restrict__ EM,
    const int* __restrict__ from_idx, const int* __restrict__ to_idx,
    float* __restrict__ loss_out)
{
    __shared__ float T[32][33];
    __shared__ float la[64][65];
    __shared__ float ce[64][128];
    __shared__ int qf[64], qt[64], cfi[64], cti[64];
    __shared__ float red[4];
    const int bb = blockIdx.x;
    const int tid = threadIdx.x;
    for (int u = tid; u < 1024; u += 256) T[u >> 5][u & 31] = plan[(size_t)bb * 1024 + u];
    if (tid < 64) {
        const int gq = 2 * bb, gc = 2 * bb + 1;
        qf[tid]  = from_idx[gq * 64 + tid] - gq * NPG;
        qt[tid]  = to_idx  [gq * 64 + tid] - gq * NPG;
        cfi[tid] = from_idx[gc * 64 + tid] - gc * NPG;
        cti[tid] = to_idx  [gc * 64 + tid] - gc * NPG;
    }
    {
        const int gc = 2 * bb + 1;
        for (int u = tid * 4; u < 8192; u += 1024) {
            const int i = u >> 7, d = u & 127;
            *(float4*)&ce[i][d] = *(const float4*)(EM + (size_t)(gc * 64 + i) * 128 + d);
        }
    }
    __syncthreads();
    {
        const int i = tid >> 2, jg = tid & 3;
        const int a = qf[i], b_ = qt[i];
#pragma unroll
        for (int u = 0; u < 16; ++u) {
            const int j = jg * 16 + u;
            const float s = T[a][cfi[j]] * T[b_][cti[j]] + T[a][cti[j]] * T[b_][cfi[j]];
            la[i][j] = s * TEMPINV;
        }
    }
    __syncthreads();
    const int l4 = tid & 3, rr = tid >> 2;
    for (int it = 0; it < SINK_ITERS; ++it) {
        {
            float x[16];
#pragma unroll
            for (int u = 0; u < 16; ++u) x[u] = la[rr][l4 * 16 + u];
            float m = x[0];
#pragma unroll
            for (int u = 1; u < 16; ++u) m = fmaxf(m, x[u]);
            m = fmaxf(m, __shfl_xor(m, 1));
            m = fmaxf(m, __shfl_xor(m, 2));
            float s = 0.f;
#pragma unroll
            for (int u = 0; u < 16; ++u) s += __expf(x[u] - m);
            s += __shfl_xor(s, 1);
            s += __shfl_xor(s, 2);
            const float lse = m + __logf(s);
#pragma unroll
            for (int u = 0; u < 16; ++u) la[rr][l4 * 16 + u] = x[u] - lse;
        }
        __syncthreads();
        {
            float x[16];
#pragma unroll
            for (int u = 0; u < 16; ++u) x[u] = la[l4 * 16 + u][rr];
            float m = x[0];
#pragma unroll
            for (int u = 1; u < 16; ++u) m = fmaxf(m, x[u]);
            m = fmaxf(m, __shfl_xor(m, 1));
            m = fmaxf(m, __shfl_xor(m, 2));
            float s = 0.f;
#pragma unroll
            for (int u = 0; u < 16; ++u) s += __expf(x[u] - m);
            s += __shfl_xor(s, 1);
            s += __shfl_xor(s, 2);
            const float lse = m + __logf(s);
#pragma unroll
            for (int u = 0; u < 16; ++u) la[l4 * 16 + u][rr] = x[u] - lse;
        }
        __syncthreads();
    }
    for (int u = tid; u < 4096; u += 256) la[u >> 6][u & 63] = __expf(la[u >> 6][u & 63]);
    __syncthreads();
    float lsum = 0.f;
    {
        const int q = tid >> 2, dg = tid & 3;
        const float* qe = EM + (size_t)((2 * bb) * 64 + q) * 128;
        for (int u = 0; u < 32; ++u) {
            const int d = dg + 4 * u;
            float pc = 0.f;
            for (int c = 0; c < 64; ++c) pc = fmaf(la[q][c], ce[c][d], pc);
            lsum += fmaxf(qe[d] - pc, 0.f);
        }
    }
#pragma unroll
    for (int off = 1; off < 64; off <<= 1) lsum += __shfl_xor(lsum, off);
    if ((tid & 63) == 0) red[tid >> 6] = lsum;
    __syncthreads();
    if (tid == 0) loss_out[bb] -= CW * (red[0] + red[1] + red[2] + red[3]);
}

// ---------------------------------------------------------------------------
extern "C" void kernel_launch(void* const* d_in, const int* in_sizes, int n_in,
                              void* d_out, int out_size, void* d_ws, size_t ws_size,
                              hipStream_t stream)
{
    const float* node_features = (const float*)d_in[0];
    const float* edge_features = (const float*)d_in[1];
    const float* enc_nw  = (const float*)d_in[2];
    const float* enc_nb  = (const float*)d_in[3];
    const float* enc_ew  = (const float*)d_in[4];
    const float* enc_eb  = (const float*)d_in[5];
    const float* msg_w1  = (const float*)d_in[6];
    const float* msg_b1  = (const float*)d_in[7];
    const float* msg_w2  = (const float*)d_in[8];
    const float* msg_b2  = (const float*)d_in[9];
    const float* rmsg_w1 = (const float*)d_in[10];
    const float* rmsg_b1 = (const float*)d_in[11];
    const float* rmsg_w2 = (const float*)d_in[12];
    const float* rmsg_b2 = (const float*)d_in[13];
    const float* upd_w1  = (const float*)d_in[14];
    const float* upd_b1  = (const float*)d_in[15];
    const float* upd_w2  = (const float*)d_in[16];
    const float* upd_b2  = (const float*)d_in[17];
    const float* sk_w1   = (const float*)d_in[18];
    const float* sk_b1   = (const float*)d_in[19];
    const float* sk_w2   = (const float*)d_in[20];
    const float* sk_b2   = (const float*)d_in[21];
    const int* from_idx  = (const int*)d_in[22];
    const int* to_idx    = (const int*)d_in[23];
    const int* qsizes    = (const int*)d_in[24];
    const int* csizes    = (const int*)d_in[25];
    float* out = (float*)d_out;

    float* ws    = (float*)d_ws;
    float* h     = ws;                          // NN*128 fp32
    float* EM    = h + (size_t)NN * 128;        // NE*128 fp32
    float* plan  = EM + (size_t)NE * 128;       // NB*1024
    float* Wcomb = plan + (size_t)NB * 1024;    // 32*512
    float* bcomb = Wcomb + 16384;               // 512
    ushort* h_bf = (ushort*)(bcomb + 512);      // NN*128
    ushort* EC2  = h_bf + (size_t)NN * 128;     // NE*512
    ushort* agg  = EC2 + (size_t)NE * 512;      // NN*128
    ushort* WhpL = agg + (size_t)NN * 128;      // 131072
    ushort* W2fL = WhpL + 131072;               // 32768
    ushort* W2rL = W2fL + 32768;                // 32768
    ushort* UW1T = W2rL + 32768;                // 65536
    ushort* UW2T = UW1T + 65536;                // 32768

    const dim3 blk(256);
    const dim3 blk512(512);

    pack2<<<1218, blk, 0, stream>>>(msg_w1, rmsg_w1, msg_b1, rmsg_b1,
                                    enc_ew, enc_eb, msg_w2, rmsg_w2, upd_w1, upd_w2,
                                    Wcomb, bcomb, WhpL, W2fL, W2rL, UW1T, UW2T);
    // node encoder: h (fp32) + h_bf
    gemm2<4, false, true, false><<<dim3(NN / 64, 1), blk, 0, stream>>>(
        node_features, 32, 32, enc_nw, 128, enc_nb, h, h_bf, 128);
    // edge encoder folded with msg layer-1 edge slice -> EC2 fragment layout
    gemm2<8, false, false, true><<<dim3(NE / 128, 4), blk, 0, stream>>>(
        edge_features, 32, 32, Wcomb, 512, bcomb, nullptr, EC2, 512);

    for (int step = 0; step < 3; ++step) {
        msg_fused<true><<<dim3(NG), blk512, 0, stream>>>(
            h_bf, EC2, WhpL, W2fL, W2rL, msg_b2, rmsg_b2, from_idx, to_idx,
            agg, nullptr);
        upd_fused<<<dim3(NN / 16), blk, 0, stream>>>(
            agg, h_bf, UW1T, upd_b1, UW2T, upd_b2, h, h_bf);
    }

    msg_fused<false><<<dim3(NG), blk512, 0, stream>>>(
        h_bf, EC2, WhpL, W2fL, W2rL, msg_b2, rmsg_b2, from_idx, to_idx,
        nullptr, EM);

    node_kernel<<<NB, blk, 0, stream>>>(
        h, sk_w1, sk_b1, sk_w2, sk_b2, qsizes, csizes, plan, out);
    edge_kernel<<<NB, blk, 0, stream>>>(
        plan, EM, from_idx, to_idx, out);
}

// Round 10
// 553.707 us; speedup vs baseline: 1.1154x; 1.0729x over previous
//
#include <hip/hip_runtime.h>
#include <math.h>

#define NPG 28
#define EPG 64
#define NB  256
#define NG  512
#define NN  14336
#define NE  32768
#define TEMPINV 10.0f
#define SINK_ITERS 20
#define CW 0.9f

typedef unsigned int uint;
typedef unsigned short ushort;
typedef __attribute__((ext_vector_type(8))) __bf16 bf16x8;
typedef __attribute__((ext_vector_type(4))) float f32x4;

__device__ __forceinline__ ushort f2bf(float x) {
    uint u = __float_as_uint(x);
    u += 0x7fffu + ((u >> 16) & 1u);
    return (ushort)(u >> 16);
}
__device__ __forceinline__ uint f2bf2(float lo, float hi) {
    return (uint)f2bf(lo) | ((uint)f2bf(hi) << 16);
}
__device__ __forceinline__ float bflo(uint w) { return __uint_as_float(w << 16); }
__device__ __forceinline__ float bfhi(uint w) { return __uint_as_float(w & 0xffff0000u); }
__device__ __forceinline__ uint relu_sum_pk(uint w1, uint w2, uint w3) {
    float lo = fmaxf(bflo(w1) + bflo(w2) + bflo(w3), 0.f);
    float hi = fmaxf(bfhi(w1) + bfhi(w2) + bfhi(w3), 0.f);
    return f2bf2(lo, hi);
}
__device__ __forceinline__ f32x4 mfma16(bf16x8 a, bf16x8 b, f32x4 c) {
    return __builtin_amdgcn_mfma_f32_16x16x32_bf16(a, b, c, 0, 0, 0);
}

// ---------------------------------------------------------------------------
// Mega-fused GNN kernel: one block = one graph, 512 threads (8 waves).
// Exploits graph-locality of edges: runs all 3 message-passing steps, the
// update MLPs, and the final EMIT messages entirely in LDS.
// Per step: build ha (bf16 frags of LDS-resident h); for p in {f,r}:
//   HP pass-half = h@Whp -> HPs (LDS);  layer-2 GEMM (HP gathers + EC2)
//   -> LDS atomic segment-sum acc_s;  then upd1 ([agg|h]@UW1 relu -> hid),
//   upd2 (hid@UW2, h += ).  Final round: EMIT -> EM (fp32), write h.
// LDS: HPs 29.1KB (aliased as hid) + acc_s 14.8KB + hs 14.8KB + idx = 59.2KB
//  -> 2 blocks/CU, all 512 blocks co-resident.
// ---------------------------------------------------------------------------
__global__ __launch_bounds__(512, 4) void gnn_fused(
    float* __restrict__ h,               // NN*128 fp32, in/out
    const ushort* __restrict__ EC2,
    const ushort* __restrict__ WhpL,
    const ushort* __restrict__ W2fL, const ushort* __restrict__ W2rL,
    const float* __restrict__ b2f, const float* __restrict__ b2r,
    const ushort* __restrict__ UW1T, const float* __restrict__ ub1,
    const ushort* __restrict__ UW2T, const float* __restrict__ ub2,
    const int* __restrict__ from_idx, const int* __restrict__ to_idx,
    float* __restrict__ EM)
{
    __shared__ ushort HPs[NPG * 520];     // 29.1 KB; aliased as hid (28x264)
    __shared__ float acc_s[NPG * 132];    // 14.8 KB, stride 132 (bank-friendly)
    __shared__ float hs[NPG * 132];       // 14.8 KB fp32 h state
    __shared__ int fl[64], tl[64];
    const int g = blockIdx.x;
    const int tid = threadIdx.x;
    const int w = tid >> 6, lane = tid & 63;
    const int li = lane & 15, quad = lane >> 4;
    const int wm = w >> 1, wn = w & 1;
    ushort* hid = &HPs[0];

    if (tid < 64) {
        fl[tid] = from_idx[g * 64 + tid] - g * NPG;
        tl[tid] = to_idx[g * 64 + tid] - g * NPG;
    }
    for (int u = tid; u < NPG * 128; u += 512)
        hs[(u >> 7) * 132 + (u & 127)] = h[(size_t)g * (NPG * 128) + u];
    __syncthreads();

#pragma unroll 1
    for (int step = 0; step < 3; ++step) {
        // ---- build ha: bf16 A-frags of current h (rows 0..31 guarded)
        uint4 ha[2][4];
#pragma unroll
        for (int mi = 0; mi < 2; ++mi) {
            const int row = mi * 16 + li;
            const int rr = (row < NPG) ? row : 0;
#pragma unroll
            for (int kb = 0; kb < 4; ++kb) {
                const float* src = &hs[rr * 132 + kb * 32 + quad * 8];
                const float4 f0 = *(const float4*)src;
                const float4 f1 = *(const float4*)(src + 4);
                uint4 o;
                o.x = f2bf2(f0.x, f0.y);
                o.y = f2bf2(f0.z, f0.w);
                o.z = f2bf2(f1.x, f1.y);
                o.w = f2bf2(f1.z, f1.w);
                ha[mi][kb] = o;
            }
        }
        for (int u = tid; u < NPG * 132; u += 512) acc_s[u] = 0.f;

        f32x4 acc[4];
#pragma unroll
        for (int j = 0; j < 4; ++j) acc[j] = f32x4{0.f, 0.f, 0.f, 0.f};

#pragma unroll 1
        for (int p = 0; p < 2; ++p) {
            {   // HP pass-half: wave w -> local cols [w*64, w*64+64)
                const int colw = w * 64;
#pragma unroll
                for (int ni = 0; ni < 4; ++ni) {
                    const int col = colw + ni * 16 + li;
                    const ushort* pb = WhpL + (size_t)(p * 512 + col) * 32 + quad * 8;
                    f32x4 c0 = f32x4{0.f, 0.f, 0.f, 0.f};
                    f32x4 c1 = f32x4{0.f, 0.f, 0.f, 0.f};
#pragma unroll
                    for (int kb = 0; kb < 4; ++kb) {
                        const bf16x8 b = __builtin_bit_cast(bf16x8,
                            *(const uint4*)(pb + (size_t)kb * 32768));
                        c0 = mfma16(__builtin_bit_cast(bf16x8, ha[0][kb]), b, c0);
                        c1 = mfma16(__builtin_bit_cast(bf16x8, ha[1][kb]), b, c1);
                    }
#pragma unroll
                    for (int r = 0; r < 4; ++r) {
                        const int r0 = quad * 4 + r;
                        HPs[r0 * 520 + col] = f2bf(c0[r]);
                        const int r1 = 16 + quad * 4 + r;
                        if (r1 < NPG) HPs[r1 * 520 + col] = f2bf(c1[r]);
                    }
                }
            }
            __syncthreads();
            if (p == 1) {
#pragma unroll
                for (int j = 0; j < 4; ++j) acc[j] = f32x4{0.f, 0.f, 0.f, 0.f};
            }
            // layer-2: wave (wm,wn): edges [wm*16,+16), cols [wn*64,+64)
            const int e = wm * 16 + li;
            const int i1 = p ? tl[e] : fl[e];
            const int i2 = p ? fl[e] : tl[e];
            const int ad1 = i1 * 520 + quad * 8;
            const int ad2 = i2 * 520 + 256 + quad * 8;
            const int ade = e * 32 + quad * 8;
            const ushort* ecb = EC2 + (size_t)(g * 2 + p) * 16384;
            const ushort* W2L = p ? W2rL : W2fL;
            const int n0 = wn * 64;
            const ushort* pb[4];
#pragma unroll
            for (int ni = 0; ni < 4; ++ni)
                pb[ni] = W2L + (size_t)(n0 + ni * 16 + li) * 32 + quad * 8;
#pragma unroll
            for (int kb = 0; kb < 8; ++kb) {
                const uint4 u1 = *(const uint4*)&HPs[ad1 + kb * 32];
                const uint4 u2 = *(const uint4*)&HPs[ad2 + kb * 32];
                const uint4 ue = *(const uint4*)(ecb + kb * 2048 + ade);
                uint4 o;
                o.x = relu_sum_pk(u1.x, u2.x, ue.x);
                o.y = relu_sum_pk(u1.y, u2.y, ue.y);
                o.z = relu_sum_pk(u1.z, u2.z, ue.z);
                o.w = relu_sum_pk(u1.w, u2.w, ue.w);
                const bf16x8 a = __builtin_bit_cast(bf16x8, o);
#pragma unroll
                for (int ni = 0; ni < 4; ++ni) {
                    const bf16x8 b = __builtin_bit_cast(bf16x8,
                        *(const uint4*)(pb[ni] + (size_t)kb * 4096));
                    acc[ni] = mfma16(a, b, acc[ni]);
                }
            }
            {   // segment-sum into acc_s (+per-edge bias, matches reference)
                const int* targ = p ? fl : tl;
                const float* bias = p ? b2r : b2f;
                float bv[4];
#pragma unroll
                for (int ni = 0; ni < 4; ++ni) bv[ni] = bias[n0 + ni * 16 + li];
#pragma unroll
                for (int r = 0; r < 4; ++r) {
                    const int loc = targ[wm * 16 + quad * 4 + r];
#pragma unroll
                    for (int ni = 0; ni < 4; ++ni)
                        atomicAdd(&acc_s[loc * 132 + n0 + ni * 16 + li],
                                  acc[ni][r] + bv[ni]);
                }
            }
            __syncthreads();
        }

        {   // ---- upd1: wave w -> cols [w*32,+32); A = [agg | h] (K=256)
            const int n0u = w * 32;
            f32x4 ua[2][2];
#pragma unroll
            for (int mi = 0; mi < 2; ++mi)
#pragma unroll
                for (int ni = 0; ni < 2; ++ni) ua[mi][ni] = f32x4{0.f, 0.f, 0.f, 0.f};
            const ushort* pb0 = UW1T + (size_t)(n0u + li) * 256 + quad * 8;
            const ushort* pb1 = UW1T + (size_t)(n0u + 16 + li) * 256 + quad * 8;
#pragma unroll
            for (int kb = 0; kb < 8; ++kb) {
                bf16x8 a[2];
                if (kb < 4) {
#pragma unroll
                    for (int mi = 0; mi < 2; ++mi) {
                        const int row = mi * 16 + li;
                        const int rr = (row < NPG) ? row : 0;
                        const float* src = &acc_s[rr * 132 + kb * 32 + quad * 8];
                        const float4 f0 = *(const float4*)src;
                        const float4 f1 = *(const float4*)(src + 4);
                        uint4 o;
                        o.x = f2bf2(f0.x, f0.y);
                        o.y = f2bf2(f0.z, f0.w);
                        o.z = f2bf2(f1.x, f1.y);
                        o.w = f2bf2(f1.z, f1.w);
                        a[mi] = __builtin_bit_cast(bf16x8, o);
                    }
                } else {
                    a[0] = __builtin_bit_cast(bf16x8, ha[0][kb - 4]);
                    a[1] = __builtin_bit_cast(bf16x8, ha[1][kb - 4]);
                }
                const bf16x8 b0 = __builtin_bit_cast(bf16x8, *(const uint4*)(pb0 + kb * 32));
                const bf16x8 b1 = __builtin_bit_cast(bf16x8, *(const uint4*)(pb1 + kb * 32));
#pragma unroll
                for (int mi = 0; mi < 2; ++mi) {
                    ua[mi][0] = mfma16(a[mi], b0, ua[mi][0]);
                    ua[mi][1] = mfma16(a[mi], b1, ua[mi][1]);
                }
            }
            const float bv0 = ub1[n0u + li], bv1 = ub1[n0u + 16 + li];
#pragma unroll
            for (int mi = 0; mi < 2; ++mi)
#pragma unroll
                for (int r = 0; r < 4; ++r) {
                    const int row = mi * 16 + quad * 4 + r;
                    if (row < NPG) {
                        hid[row * 264 + n0u + li] = f2bf(fmaxf(ua[mi][0][r] + bv0, 0.f));
                        hid[row * 264 + n0u + 16 + li] = f2bf(fmaxf(ua[mi][1][r] + bv1, 0.f));
                    }
                }
        }
        __syncthreads();
        {   // ---- upd2: wave w -> cols [w*16,+16); K=256 over hid; h +=
            const int n0u = w * 16;
            f32x4 ua[2];
            ua[0] = f32x4{0.f, 0.f, 0.f, 0.f};
            ua[1] = f32x4{0.f, 0.f, 0.f, 0.f};
            const ushort* pb0 = UW2T + (size_t)(n0u + li) * 256 + quad * 8;
#pragma unroll
            for (int kb = 0; kb < 8; ++kb) {
                bf16x8 a[2];
#pragma unroll
                for (int mi = 0; mi < 2; ++mi) {
                    const int row = mi * 16 + li;
                    const int rr = (row < NPG) ? row : 0;
                    a[mi] = __builtin_bit_cast(bf16x8,
                        *(const uint4*)&hid[rr * 264 + kb * 32 + quad * 8]);
                }
                const bf16x8 b0 = __builtin_bit_cast(bf16x8, *(const uint4*)(pb0 + kb * 32));
                ua[0] = mfma16(a[0], b0, ua[0]);
                ua[1] = mfma16(a[1], b0, ua[1]);
            }
            const float bv = ub2[n0u + li];
#pragma unroll
            for (int mi = 0; mi < 2; ++mi)
#pragma unroll
                for (int r = 0; r < 4; ++r) {
                    const int row = mi * 16 + quad * 4 + r;
                    if (row < NPG)
                        hs[row * 132 + n0u + li] += ua[mi][r] + bv;
                }
        }
        __syncthreads();
    }

    // ---- final messages (EMIT): HP from final h, both passes into shared acc
    {
        uint4 ha[2][4];
#pragma unroll
        for (int mi = 0; mi < 2; ++mi) {
            const int row = mi * 16 + li;
            const int rr = (row < NPG) ? row : 0;
#pragma unroll
            for (int kb = 0; kb < 4; ++kb) {
                const float* src = &hs[rr * 132 + kb * 32 + quad * 8];
                const float4 f0 = *(const float4*)src;
                const float4 f1 = *(const float4*)(src + 4);
                uint4 o;
                o.x = f2bf2(f0.x, f0.y);
                o.y = f2bf2(f0.z, f0.w);
                o.z = f2bf2(f1.x, f1.y);
                o.w = f2bf2(f1.z, f1.w);
                ha[mi][kb] = o;
            }
        }
        f32x4 acc[4];
#pragma unroll
        for (int j = 0; j < 4; ++j) acc[j] = f32x4{0.f, 0.f, 0.f, 0.f};
        const int n0 = wn * 64;
#pragma unroll 1
        for (int p = 0; p < 2; ++p) {
            {
                const int colw = w * 64;
#pragma unroll
                for (int ni = 0; ni < 4; ++ni) {
                    const int col = colw + ni * 16 + li;
                    const ushort* pb = WhpL + (size_t)(p * 512 + col) * 32 + quad * 8;
                    f32x4 c0 = f32x4{0.f, 0.f, 0.f, 0.f};
                    f32x4 c1 = f32x4{0.f, 0.f, 0.f, 0.f};
#pragma unroll
                    for (int kb = 0; kb < 4; ++kb) {
                        const bf16x8 b = __builtin_bit_cast(bf16x8,
                            *(const uint4*)(pb + (size_t)kb * 32768));
                        c0 = mfma16(__builtin_bit_cast(bf16x8, ha[0][kb]), b, c0);
                        c1 = mfma16(__builtin_bit_cast(bf16x8, ha[1][kb]), b, c1);
                    }
#pragma unroll
                    for (int r = 0; r < 4; ++r) {
                        const int r0 = quad * 4 + r;
                        HPs[r0 * 520 + col] = f2bf(c0[r]);
                        const int r1 = 16 + quad * 4 + r;
                        if (r1 < NPG) HPs[r1 * 520 + col] = f2bf(c1[r]);
                    }
                }
            }
            __syncthreads();
            const int e = wm * 16 + li;
            const int i1 = p ? tl[e] : fl[e];
            const int i2 = p ? fl[e] : tl[e];
            const int ad1 = i1 * 520 + quad * 8;
            const int ad2 = i2 * 520 + 256 + quad * 8;
            const int ade = e * 32 + quad * 8;
            const ushort* ecb = EC2 + (size_t)(g * 2 + p) * 16384;
            const ushort* W2L = p ? W2rL : W2fL;
            const ushort* pb[4];
#pragma unroll
            for (int ni = 0; ni < 4; ++ni)
                pb[ni] = W2L + (size_t)(n0 + ni * 16 + li) * 32 + quad * 8;
#pragma unroll
            for (int kb = 0; kb < 8; ++kb) {
                const uint4 u1 = *(const uint4*)&HPs[ad1 + kb * 32];
                const uint4 u2 = *(const uint4*)&HPs[ad2 + kb * 32];
                const uint4 ue = *(const uint4*)(ecb + kb * 2048 + ade);
                uint4 o;
                o.x = relu_sum_pk(u1.x, u2.x, ue.x);
                o.y = relu_sum_pk(u1.y, u2.y, ue.y);
                o.z = relu_sum_pk(u1.z, u2.z, ue.z);
                o.w = relu_sum_pk(u1.w, u2.w, ue.w);
                const bf16x8 a = __builtin_bit_cast(bf16x8, o);
#pragma unroll
                for (int ni = 0; ni < 4; ++ni) {
                    const bf16x8 b = __builtin_bit_cast(bf16x8,
                        *(const uint4*)(pb[ni] + (size_t)kb * 4096));
                    acc[ni] = mfma16(a, b, acc[ni]);
                }
            }
            __syncthreads();
        }
        float bv[4];
#pragma unroll
        for (int ni = 0; ni < 4; ++ni)
            bv[ni] = b2f[n0 + ni * 16 + li] + b2r[n0 + ni * 16 + li];
#pragma unroll
        for (int r = 0; r < 4; ++r) {
            const int erow = g * 64 + wm * 16 + quad * 4 + r;
#pragma unroll
            for (int ni = 0; ni < 4; ++ni)
                EM[(size_t)erow * 128 + n0 + ni * 16 + li] = acc[ni][r] + bv[ni];
        }
    }
    // write back final h (fp32) for the node head
    for (int u = tid; u < NPG * 128; u += 512)
        h[(size_t)g * (NPG * 128) + u] = hs[(u >> 7) * 132 + (u & 127)];
}

// ---------------------------------------------------------------------------
// fp32 tiled GEMM for K=32 encoders (verified core).
// OUT2: also write bf16. ECL: scatter into EC2 fragment layout.
// ---------------------------------------------------------------------------
template<int TM, bool OUTBF, bool OUT2, bool ECL>
__global__ __launch_bounds__(256) void gemm2(
    const float* __restrict__ A, int lda, int K,
    const float* __restrict__ W, int ldw, const float* __restrict__ bias,
    float* __restrict__ C, ushort* __restrict__ Cb, int ldc)
{
    constexpr int BM = TM * 16;
    constexpr int AV = BM / 64;
    __shared__ float As[16][BM + 4];
    __shared__ float Bs[16][132];
    const int tid = threadIdx.x;
    const int m0 = blockIdx.x * BM;
    const int n0 = blockIdx.y * 128;
    const int tx = tid & 15, ty = tid >> 4;
    const int arow = (AV == 2) ? (tid >> 1) : (tid >> 2);
    const int a0   = (AV == 2) ? ((tid & 1) * 8) : ((tid & 3) * 4);
    const int brow = ty;
    const int bcol = tx * 8;
    const int nch = K >> 4;

    float4 aC[2], bC[2], aN[2], bN[2];
    float acc[TM][8];
#pragma unroll
    for (int i = 0; i < TM; ++i)
#pragma unroll
        for (int j = 0; j < 8; ++j) acc[i][j] = 0.f;

    {
        const float* src = A + (size_t)(m0 + arow) * lda + a0;
        aC[0] = *(const float4*)src;
        if (AV == 2) aC[1] = *(const float4*)(src + 4);
        const float* bsrc = W + (size_t)brow * ldw + n0 + bcol;
        bC[0] = *(const float4*)bsrc;
        bC[1] = *(const float4*)(bsrc + 4);
    }

    for (int ch = 0; ch < nch; ++ch) {
        {
            const float* f = (const float*)aC;
#pragma unroll
            for (int i = 0; i < AV * 4; ++i) As[a0 + i][arow] = f[i];
            *(float4*)&Bs[brow][bcol]     = bC[0];
            *(float4*)&Bs[brow][bcol + 4] = bC[1];
        }
        __syncthreads();
        if (ch + 1 < nch) {
            const int kc = (ch + 1) << 4;
            const float* src = A + (size_t)(m0 + arow) * lda + kc + a0;
            aN[0] = *(const float4*)src;
            if (AV == 2) aN[1] = *(const float4*)(src + 4);
            const float* bsrc = W + (size_t)(kc + brow) * ldw + n0 + bcol;
            bN[0] = *(const float4*)bsrc;
            bN[1] = *(const float4*)(bsrc + 4);
        }
#pragma unroll
        for (int kk = 0; kk < 16; ++kk) {
            float afr[TM], bfr[8];
#pragma unroll
            for (int i = 0; i < TM; i += 4)
                *(float4*)&afr[i] = *(const float4*)&As[kk][ty * TM + i];
            *(float4*)&bfr[0] = *(const float4*)&Bs[kk][tx * 8];
            *(float4*)&bfr[4] = *(const float4*)&Bs[kk][tx * 8 + 4];
#pragma unroll
            for (int i = 0; i < TM; ++i)
#pragma unroll
                for (int j = 0; j < 8; ++j) acc[i][j] = fmaf(afr[i], bfr[j], acc[i][j]);
        }
        __syncthreads();
        aC[0] = aN[0]; aC[1] = aN[1];
        bC[0] = bN[0]; bC[1] = bN[1];
    }
#pragma unroll
    for (int i = 0; i < TM; ++i) {
        const int row = m0 + ty * TM + i;
#pragma unroll
        for (int j = 0; j < 8; ++j) {
            const int col = n0 + tx * 8 + j;
            float v = acc[i][j] + bias[col];
            if (ECL) {
                const int gg = row >> 6, eloc = row & 63;
                const int p = col >> 8, kb = (col >> 5) & 7, jj = col & 31;
                Cb[(size_t)(((gg * 2 + p) * 8 + kb)) * 2048 + eloc * 32 + jj] = f2bf(v);
            } else if (OUTBF) {
                Cb[(size_t)row * ldc + col] = f2bf(v);
            } else {
                C[(size_t)row * ldc + col] = v;
                if (OUT2) Cb[(size_t)row * ldc + col] = f2bf(v);
            }
        }
    }
}

// ---------------------------------------------------------------------------
// Weight packing (verified)
// ---------------------------------------------------------------------------
__global__ __launch_bounds__(256) void pack2(
    const float* __restrict__ msg_w1, const float* __restrict__ rmsg_w1,
    const float* __restrict__ msg_b1, const float* __restrict__ rmsg_b1,
    const float* __restrict__ enc_ew, const float* __restrict__ enc_eb,
    const float* __restrict__ msg_w2, const float* __restrict__ rmsg_w2,
    const float* __restrict__ upd_w1, const float* __restrict__ upd_w2,
    float* __restrict__ Wcomb, float* __restrict__ bcomb,
    ushort* __restrict__ WhpL, ushort* __restrict__ W2fL, ushort* __restrict__ W2rL,
    ushort* __restrict__ UW1T, ushort* __restrict__ UW2T)
{
    const int gid = blockIdx.x, tid = threadIdx.x;
    if (gid < 64) {
        const int idx = gid * 256 + tid;
        const int a = idx >> 9, n = idx & 511;
        const float* Wsrc = (n < 256) ? msg_w1 : rmsg_w1;
        const int nc = n & 255;
        float s = 0.f;
        for (int j = 0; j < 128; ++j)
            s = fmaf(enc_ew[a * 128 + j], Wsrc[(256 + j) * 256 + nc], s);
        Wcomb[idx] = s;
    } else if (gid < 66) {
        const int n = (gid - 64) * 256 + tid;
        const float* Wsrc = (n < 256) ? msg_w1 : rmsg_w1;
        const float* bsrc = (n < 256) ? msg_b1 : rmsg_b1;
        const int nc = n & 255;
        float s = bsrc[nc];
        for (int j = 0; j < 128; ++j)
            s = fmaf(enc_eb[j], Wsrc[(256 + j) * 256 + nc], s);
        bcomb[n] = s;
    } else if (gid < 578) {
        const int idx = (gid - 66) * 256 + tid;        // [0,131072)
        const int n = idx >> 7, k = idx & 127;
        const float* Wsrc = (n < 512) ? msg_w1 : rmsg_w1;
        const int part = (n >> 8) & 1, col = n & 255;
        WhpL[(size_t)(k >> 5) * 32768 + n * 32 + (k & 31)] =
            f2bf(Wsrc[(part * 128 + k) * 256 + col]);
    } else if (gid < 706) {
        const int idx = (gid - 578) * 256 + tid;       // [0,32768)
        const int n = idx >> 8, k = idx & 255;
        W2fL[(size_t)(k >> 5) * 4096 + n * 32 + (k & 31)] = f2bf(msg_w2[k * 128 + n]);
    } else if (gid < 834) {
        const int idx = (gid - 706) * 256 + tid;
        const int n = idx >> 8, k = idx & 255;
        W2rL[(size_t)(k >> 5) * 4096 + n * 32 + (k & 31)] = f2bf(rmsg_w2[k * 128 + n]);
    } else if (gid < 1090) {
        const int idx = (gid - 834) * 256 + tid;
        const int n = idx >> 8, k = idx & 255;
        UW1T[idx] = f2bf(upd_w1[k * 256 + n]);
    } else {
        const int idx = (gid - 1090) * 256 + tid;
        const int n = idx >> 8, k = idx & 255;
        UW2T[idx] = f2bf(upd_w2[k * 128 + n]);
    }
}

// ---------------------------------------------------------------------------
// Node head (verified)
// ---------------------------------------------------------------------------
__global__ __launch_bounds__(256) void node_kernel(
    const float* __restrict__ h,
    const float* __restrict__ w1, const float* __restrict__ b1,
    const float* __restrict__ w2, const float* __restrict__ b2,
    const int* __restrict__ qsz, const int* __restrict__ csz,
    float* __restrict__ plan_out, float* __restrict__ loss_out)
{
    __shared__ float qn[32][128];
    __shared__ float cn[32][128];
    __shared__ float t1[32][64];
    __shared__ float mq[32][68];
    __shared__ float mc[32][68];
    __shared__ float la[32][33];
    __shared__ float red[4];
    const int bb = blockIdx.x;
    const int tid = threadIdx.x;
    const int qs = qsz[bb], cs = csz[bb];
    for (int u = tid * 4; u < 4096; u += 1024) {
        const int p = u >> 7, d = u & 127;
        float4 zq = make_float4(0.f, 0.f, 0.f, 0.f), zc = zq;
        if (p < NPG) {
            zq = *(const float4*)(h + (size_t)((2 * bb) * NPG + p) * 128 + d);
            zc = *(const float4*)(h + (size_t)((2 * bb + 1) * NPG + p) * 128 + d);
        }
        *(float4*)&qn[p][d] = zq;
        *(float4*)&cn[p][d] = zc;
    }
    __syncthreads();
    const int col = tid & 63;
    const int rg  = tid >> 6;
    for (int s = 0; s < 2; ++s) {
        const float (*src)[128] = s ? cn : qn;
        float (*dst)[68] = s ? mc : mq;
        const int sz = s ? cs : qs;
        float a8[8];
#pragma unroll
        for (int u = 0; u < 8; ++u) a8[u] = b1[col];
        for (int k = 0; k < 128; ++k) {
            const float wv = w1[k * 64 + col];
#pragma unroll
            for (int u = 0; u < 8; ++u) a8[u] = fmaf(src[rg + 4 * u][k], wv, a8[u]);
        }
#pragma unroll
        for (int u = 0; u < 8; ++u) t1[rg + 4 * u][col] = fmaxf(a8[u], 0.f);
        __syncthreads();
#pragma unroll
        for (int u = 0; u < 8; ++u) a8[u] = b2[col];
        for (int k = 0; k < 64; ++k) {
            const float wv = w2[k * 64 + col];
#pragma unroll
            for (int u = 0; u < 8; ++u) a8[u] = fmaf(t1[rg + 4 * u][k], wv, a8[u]);
        }
#pragma unroll
        for (int u = 0; u < 8; ++u) {
            const int r = rg + 4 * u;
            dst[r][col] = (r < sz) ? a8[u] : 0.f;
        }
        __syncthreads();
    }
    {
        const int q = tid >> 3, cg = tid & 7;
#pragma unroll
        for (int u = 0; u < 4; ++u) {
            const int c = cg + 8 * u;
            float s = 0.f;
            for (int d = 0; d < 64; ++d) s = fmaf(mq[q][d], mc[c][d], s);
            la[q][c] = s * TEMPINV;
        }
    }
    __syncthreads();
    const int l8 = tid & 7, rq = tid >> 3;
    for (int it = 0; it < SINK_ITERS; ++it) {
        {
            float x[4];
#pragma unroll
            for (int u = 0; u < 4; ++u) x[u] = la[rq][l8 * 4 + u];
            float m = fmaxf(fmaxf(x[0], x[1]), fmaxf(x[2], x[3]));
            m = fmaxf(m, __shfl_xor(m, 1));
            m = fmaxf(m, __shfl_xor(m, 2));
            m = fmaxf(m, __shfl_xor(m, 4));
            float s = __expf(x[0] - m) + __expf(x[1] - m) + __expf(x[2] - m) + __expf(x[3] - m);
            s += __shfl_xor(s, 1);
            s += __shfl_xor(s, 2);
            s += __shfl_xor(s, 4);
            const float lse = m + __logf(s);
#pragma unroll
            for (int u = 0; u < 4; ++u) la[rq][l8 * 4 + u] = x[u] - lse;
        }
        __syncthreads();
        {
            float x[4];
#pragma unroll
            for (int u = 0; u < 4; ++u) x[u] = la[l8 * 4 + u][rq];
            float m = fmaxf(fmaxf(x[0], x[1]), fmaxf(x[2], x[3]));
            m = fmaxf(m, __shfl_xor(m, 1));
            m = fmaxf(m, __shfl_xor(m, 2));
            m = fmaxf(m, __shfl_xor(m, 4));
            float s = __expf(x[0] - m) + __expf(x[1] - m) + __expf(x[2] - m) + __expf(x[3] - m);
            s += __shfl_xor(s, 1);
            s += __shfl_xor(s, 2);
            s += __shfl_xor(s, 4);
            const float lse = m + __logf(s);
#pragma unroll
            for (int u = 0; u < 4; ++u) la[l8 * 4 + u][rq] = x[u] - lse;
        }
        __syncthreads();
    }
    for (int u = tid; u < 1024; u += 256) {
        const int q = u >> 5, c = u & 31;
        const float p = __expf(la[q][c]);
        la[q][c] = p;
        plan_out[(size_t)bb * 1024 + u] = p;
    }
    __syncthreads();
    float lsum = 0.f;
    {
        const int q = tid >> 3, dg = tid & 7;
        for (int u = 0; u < 16; ++u) {
            const int d = dg + 8 * u;
            float pc = 0.f;
#pragma unroll
            for (int c = 0; c < 32; ++c) pc = fmaf(la[q][c], cn[c][d], pc);
            lsum += fmaxf(qn[q][d] - pc, 0.f);
        }
    }
#pragma unroll
    for (int off = 1; off < 64; off <<= 1) lsum += __shfl_xor(lsum, off);
    if ((tid & 63) == 0) red[tid >> 6] = lsum;
    __syncthreads();
    if (tid == 0) loss_out[bb] = -(red[0] + red[1] + red[2] + red[3]);
}

// ---------------------------------------------------------------------------
// Edge head (verified)
// ---------------------------------------------------------------------------
__global__ __launch_bounds__(256) void edge_kernel(
    const float* __restrict__ plan, const float* __restrict__ EM,
    const int* __restrict__ from_idx, const int* __restrict__ to_idx,
    float* __restrict__ loss_out)
{
    __shared__ float T[32][33];
    __shared__ float la[64][65];
    __shared__ float ce[64][128];
    __shared__ int qf[64], qt[64], cfi[64], cti[64];
    __shared__ float red[4];
    const int bb = blockIdx.x;
    const int tid = threadIdx.x;
    for (int u = tid; u < 1024; u += 256) T[u >> 5][u & 31] = plan[(size_t)bb * 1024 + u];
    if (tid < 64) {
        const int gq = 2 * bb, gc = 2 * bb + 1;
        qf[tid]  = from_idx[gq * 64 + tid] - gq * NPG;
        qt[tid]  = to_idx  [gq * 64 + tid] - gq * NPG;
        cfi[tid] = from_idx[gc * 64 + tid] - gc * NPG;
        cti[tid] = to_idx  [gc * 64 + tid] - gc * NPG;
    }
    {
        const int gc = 2 * bb + 1;
        for (int u = tid * 4; u < 8192; u += 1024) {
            const int i = u >> 7, d = u & 127;
            *(float4*)&ce[i][d] = *(const float4*)(EM + (size_t)(gc * 64 + i) * 128 + d);
        }
    }
    __syncthreads();
    {
        const int i = tid >> 2, jg = tid & 3;
        const int a = qf[i], b_ = qt[i];
#pragma unroll
        for (int u = 0; u < 16; ++u) {
            const int j = jg * 16 + u;
            const float s = T[a][cfi[j]] * T[b_][cti[j]] + T[a][cti[j]] * T[b_][cfi[j]];
            la[i][j] = s * TEMPINV;
        }
    }
    __syncthreads();
    const int l4 = tid & 3, rr = tid >> 2;
    for (int it = 0; it < SINK_ITERS; ++it) {
        {
            float x[16];
#pragma unroll
            for (int u = 0; u < 16; ++u) x[u] = la[rr][l4 * 16 + u];
            float m = x[0];
#pragma unroll
            for (int u = 1; u < 16; ++u) m = fmaxf(m, x[u]);
            m = fmaxf(m, __shfl_xor(m, 1));
            m = fmaxf(m, __shfl_xor(m, 2));
            float s = 0.f;
#pragma unroll
            for (int u = 0; u < 16; ++u) s += __expf(x[u] - m);
            s += __shfl_xor(s, 1);
            s += __shfl_xor(s, 2);
            const float lse = m + __logf(s);
#pragma unroll
            for (int u = 0; u < 16; ++u) la[rr][l4 * 16 + u] = x[u] - lse;
        }
        __syncthreads();
        {
            float x[16];
#pragma unroll
            for (int u = 0; u < 16; ++u) x[u] = la[l4 * 16 + u][rr];
            float m = x[0];
#pragma unroll
            for (int u = 1; u < 16; ++u) m = fmaxf(m, x[u]);
            m = fmaxf(m, __shfl_xor(m, 1));
            m = fmaxf(m, __shfl_xor(m, 2));
            float s = 0.f;
#pragma unroll
            for (int u = 0; u < 16; ++u) s += __expf(x[u] - m);
            s += __shfl_xor(s, 1);
            s += __shfl_xor(s, 2);
            const float lse = m + __logf(s);
#pragma unroll
            for (int u = 0; u < 16; ++u) la[l4 * 16 + u][rr] = x[u] - lse;
        }
        __syncthreads();
    }
    for (int u = tid; u < 4096; u += 256) la[u >> 6][u & 63] = __expf(la[u >> 6][u & 63]);
    __syncthreads();
    float lsum = 0.f;
    {
        const int q = tid >> 2, dg = tid & 3;
        const float* qe = EM + (size_t)((2 * bb) * 64 + q) * 128;
        for (int u = 0; u < 32; ++u) {
            const int d = dg + 4 * u;
            float pc = 0.f;
            for (int c = 0; c < 64; ++c) pc = fmaf(la[q][c], ce[c][d], pc);
            lsum += fmaxf(qe[d] - pc, 0.f);
        }
    }
#pragma unroll
    for (int off = 1; off < 64; off <<= 1) lsum += __shfl_xor(lsum, off);
    if ((tid & 63) == 0) red[tid >> 6] = lsum;
    __syncthreads();
    if (tid == 0) loss_out[bb] -= CW * (red[0] + red[1] + red[2] + red[3]);
}

// ---------------------------------------------------------------------------
extern "C" void kernel_launch(void* const* d_in, const int* in_sizes, int n_in,
                              void* d_out, int out_size, void* d_ws, size_t ws_size,
                              hipStream_t stream)
{
    const float* node_features = (const float*)d_in[0];
    const float* edge_features = (const float*)d_in[1];
    const float* enc_nw  = (const float*)d_in[2];
    const float* enc_nb  = (const float*)d_in[3];
    const float* enc_ew  = (const float*)d_in[4];
    const float* enc_eb  = (const float*)d_in[5];
    const float* msg_w1  = (const float*)d_in[6];
    const float* msg_b1  = (const float*)d_in[7];
    const float* msg_w2  = (const float*)d_in[8];
    const float* msg_b2  = (const float*)d_in[9];
    const float* rmsg_w1 = (const float*)d_in[10];
    const float* rmsg_b1 = (const float*)d_in[11];
    const float* rmsg_w2 = (const float*)d_in[12];
    const float* rmsg_b2 = (const float*)d_in[13];
    const float* upd_w1  = (const float*)d_in[14];
    const float* upd_b1  = (const float*)d_in[15];
    const float* upd_w2  = (const float*)d_in[16];
    const float* upd_b2  = (const float*)d_in[17];
    const float* sk_w1   = (const float*)d_in[18];
    const float* sk_b1   = (const float*)d_in[19];
    const float* sk_w2   = (const float*)d_in[20];
    const float* sk_b2   = (const float*)d_in[21];
    const int* from_idx  = (const int*)d_in[22];
    const int* to_idx    = (const int*)d_in[23];
    const int* qsizes    = (const int*)d_in[24];
    const int* csizes    = (const int*)d_in[25];
    float* out = (float*)d_out;

    float* ws    = (float*)d_ws;
    float* h     = ws;                          // NN*128 fp32
    float* EM    = h + (size_t)NN * 128;        // NE*128 fp32
    float* plan  = EM + (size_t)NE * 128;       // NB*1024
    float* Wcomb = plan + (size_t)NB * 1024;    // 32*512
    float* bcomb = Wcomb + 16384;               // 512
    ushort* EC2  = (ushort*)(bcomb + 512);      // NE*512
    ushort* WhpL = EC2 + (size_t)NE * 512;      // 131072
    ushort* W2fL = WhpL + 131072;               // 32768
    ushort* W2rL = W2fL + 32768;                // 32768
    ushort* UW1T = W2rL + 32768;                // 65536
    ushort* UW2T = UW1T + 65536;                // 32768

    const dim3 blk(256);
    const dim3 blk512(512);

    pack2<<<1218, blk, 0, stream>>>(msg_w1, rmsg_w1, msg_b1, rmsg_b1,
                                    enc_ew, enc_eb, msg_w2, rmsg_w2, upd_w1, upd_w2,
                                    Wcomb, bcomb, WhpL, W2fL, W2rL, UW1T, UW2T);
    // node encoder: h fp32
    gemm2<4, false, false, false><<<dim3(NN / 64, 1), blk, 0, stream>>>(
        node_features, 32, 32, enc_nw, 128, enc_nb, h, nullptr, 128);
    // edge encoder folded with msg layer-1 edge slice -> EC2 fragment layout
    gemm2<8, false, false, true><<<dim3(NE / 128, 4), blk, 0, stream>>>(
        edge_features, 32, 32, Wcomb, 512, bcomb, nullptr, EC2, 512);

    // all 3 GNN steps + final messages, one dispatch
    gnn_fused<<<dim3(NG), blk512, 0, stream>>>(
        h, EC2, WhpL, W2fL, W2rL, msg_b2, rmsg_b2,
        UW1T, upd_b1, UW2T, upd_b2, from_idx, to_idx, EM);

    node_kernel<<<NB, blk, 0, stream>>>(
        h, sk_w1, sk_b1, sk_w2, sk_b2, qsizes, csizes, plan, out);
    edge_kernel<<<NB, blk, 0, stream>>>(
        plan, EM, from_idx, to_idx, out);
}

// Round 11
// 540.785 us; speedup vs baseline: 1.1421x; 1.0239x over previous
//
#include <hip/hip_runtime.h>
#include <math.h>

#define NPG 28
#define EPG 64
#define NB  256
#define NG  512
#define NN  14336
#define NE  32768
#define TEMPINV 10.0f
#define SINK_ITERS 20
#define CW 0.9f

typedef unsigned int uint;
typedef unsigned short ushort;
typedef __attribute__((ext_vector_type(8))) __bf16 bf16x8;
typedef __attribute__((ext_vector_type(4))) float f32x4;

__device__ __forceinline__ ushort f2bf(float x) {
    uint u = __float_as_uint(x);
    u += 0x7fffu + ((u >> 16) & 1u);
    return (ushort)(u >> 16);
}
__device__ __forceinline__ uint f2bf2(float lo, float hi) {
    return (uint)f2bf(lo) | ((uint)f2bf(hi) << 16);
}
__device__ __forceinline__ float bflo(uint w) { return __uint_as_float(w << 16); }
__device__ __forceinline__ float bfhi(uint w) { return __uint_as_float(w & 0xffff0000u); }
__device__ __forceinline__ uint relu_sum_pk(uint w1, uint w2, uint w3) {
    float lo = fmaxf(bflo(w1) + bflo(w2) + bflo(w3), 0.f);
    float hi = fmaxf(bfhi(w1) + bfhi(w2) + bfhi(w3), 0.f);
    return f2bf2(lo, hi);
}
__device__ __forceinline__ f32x4 mfma16(bf16x8 a, bf16x8 b, f32x4 c) {
    return __builtin_amdgcn_mfma_f32_16x16x32_bf16(a, b, c, 0, 0, 0);
}

// ---------------------------------------------------------------------------
// Mega-fused GNN kernel v2: one block = TWO graphs, 512 threads (8 waves).
// Every weight fragment loaded once is used for both graphs (halves weight
// traffic and per-phase latency overhead vs v1). All 3 steps + final EMIT
// in LDS. LDS: 2x(HPs 29.1 + acc 14.8 + hs 14.8) + idx = ~116KB -> 1 blk/CU,
// 256 blocks all co-resident.
// ---------------------------------------------------------------------------
__global__ __launch_bounds__(512, 2) void gnn_fused(
    float* __restrict__ h,               // NN*128 fp32, in/out
    const ushort* __restrict__ EC2,
    const ushort* __restrict__ WhpL,
    const ushort* __restrict__ W2fL, const ushort* __restrict__ W2rL,
    const float* __restrict__ b2f, const float* __restrict__ b2r,
    const ushort* __restrict__ UW1T, const float* __restrict__ ub1,
    const ushort* __restrict__ UW2T, const float* __restrict__ ub2,
    const int* __restrict__ from_idx, const int* __restrict__ to_idx,
    float* __restrict__ EM)
{
    __shared__ ushort HPs[2][NPG * 520];   // per-graph pass-half; alias: hid
    __shared__ float acc_s[2][NPG * 132];
    __shared__ float hs[2][NPG * 132];
    __shared__ int fl[2][64], tl[2][64];
    const int g = blockIdx.x;              // block handles graphs 2g, 2g+1
    const int tid = threadIdx.x;
    const int w = tid >> 6, lane = tid & 63;
    const int li = lane & 15, quad = lane >> 4;
    const int wm = w >> 1, wn = w & 1;

    if (tid < 128) {
        const int gr = tid >> 6, e = tid & 63;
        fl[gr][e] = from_idx[(2 * g + gr) * 64 + e] - (2 * g + gr) * NPG;
        tl[gr][e] = to_idx[(2 * g + gr) * 64 + e] - (2 * g + gr) * NPG;
    }
    for (int u = tid; u < 2 * NPG * 128; u += 512) {
        const int gr = u / (NPG * 128), v = u % (NPG * 128);
        hs[gr][(v >> 7) * 132 + (v & 127)] =
            h[((size_t)(2 * g) * NPG * 128) + (size_t)gr * NPG * 128 + v];
    }
    __syncthreads();

#pragma unroll 1
    for (int step = 0; step < 3; ++step) {
        // build bf16 A-frags of current h for both graphs
        uint4 ha[2][2][4];
#pragma unroll
        for (int gr = 0; gr < 2; ++gr)
#pragma unroll
            for (int mi = 0; mi < 2; ++mi) {
                const int row = mi * 16 + li;
                const int rr = (row < NPG) ? row : 0;
#pragma unroll
                for (int kb = 0; kb < 4; ++kb) {
                    const float* src = &hs[gr][rr * 132 + kb * 32 + quad * 8];
                    const float4 f0 = *(const float4*)src;
                    const float4 f1 = *(const float4*)(src + 4);
                    uint4 o;
                    o.x = f2bf2(f0.x, f0.y);
                    o.y = f2bf2(f0.z, f0.w);
                    o.z = f2bf2(f1.x, f1.y);
                    o.w = f2bf2(f1.z, f1.w);
                    ha[gr][mi][kb] = o;
                }
            }
        for (int u = tid; u < 2 * NPG * 132; u += 512)
            acc_s[u / (NPG * 132)][u % (NPG * 132)] = 0.f;

#pragma unroll 1
        for (int p = 0; p < 2; ++p) {
            {   // HP pass-half: wave w -> cols [w*64,+64), both graphs
                const int colw = w * 64;
#pragma unroll
                for (int ni = 0; ni < 4; ++ni) {
                    const int col = colw + ni * 16 + li;
                    const ushort* pb = WhpL + (size_t)(p * 512 + col) * 32 + quad * 8;
                    f32x4 c[2][2];
#pragma unroll
                    for (int gr = 0; gr < 2; ++gr)
#pragma unroll
                        for (int mi = 0; mi < 2; ++mi) c[gr][mi] = f32x4{0.f, 0.f, 0.f, 0.f};
#pragma unroll
                    for (int kb = 0; kb < 4; ++kb) {
                        const bf16x8 b = __builtin_bit_cast(bf16x8,
                            *(const uint4*)(pb + (size_t)kb * 32768));
#pragma unroll
                        for (int gr = 0; gr < 2; ++gr) {
                            c[gr][0] = mfma16(__builtin_bit_cast(bf16x8, ha[gr][0][kb]), b, c[gr][0]);
                            c[gr][1] = mfma16(__builtin_bit_cast(bf16x8, ha[gr][1][kb]), b, c[gr][1]);
                        }
                    }
#pragma unroll
                    for (int gr = 0; gr < 2; ++gr)
#pragma unroll
                        for (int r = 0; r < 4; ++r) {
                            const int r0 = quad * 4 + r;
                            HPs[gr][r0 * 520 + col] = f2bf(c[gr][0][r]);
                            const int r1 = 16 + quad * 4 + r;
                            if (r1 < NPG) HPs[gr][r1 * 520 + col] = f2bf(c[gr][1][r]);
                        }
                }
            }
            __syncthreads();

            // layer-2: wave (wm,wn): edges [wm*16,+16), cols [wn*64,+64), both graphs
            const int e = wm * 16 + li;
            const int n0 = wn * 64;
            int ad1[2], ad2[2];
            const ushort* ecb[2];
#pragma unroll
            for (int gr = 0; gr < 2; ++gr) {
                const int i1 = p ? tl[gr][e] : fl[gr][e];
                const int i2 = p ? fl[gr][e] : tl[gr][e];
                ad1[gr] = i1 * 520 + quad * 8;
                ad2[gr] = i2 * 520 + 256 + quad * 8;
                ecb[gr] = EC2 + (size_t)((2 * g + gr) * 2 + p) * 16384 + e * 32 + quad * 8;
            }
            const ushort* W2L = p ? W2rL : W2fL;
            const ushort* pb[4];
#pragma unroll
            for (int ni = 0; ni < 4; ++ni)
                pb[ni] = W2L + (size_t)(n0 + ni * 16 + li) * 32 + quad * 8;

            f32x4 acc[2][4];
#pragma unroll
            for (int gr = 0; gr < 2; ++gr)
#pragma unroll
                for (int j = 0; j < 4; ++j) acc[gr][j] = f32x4{0.f, 0.f, 0.f, 0.f};
#pragma unroll
            for (int kb = 0; kb < 8; ++kb) {
                bf16x8 b[4];
#pragma unroll
                for (int ni = 0; ni < 4; ++ni)
                    b[ni] = __builtin_bit_cast(bf16x8,
                        *(const uint4*)(pb[ni] + (size_t)kb * 4096));
#pragma unroll
                for (int gr = 0; gr < 2; ++gr) {
                    const uint4 u1 = *(const uint4*)&HPs[gr][ad1[gr] + kb * 32];
                    const uint4 u2 = *(const uint4*)&HPs[gr][ad2[gr] + kb * 32];
                    const uint4 ue = *(const uint4*)(ecb[gr] + kb * 2048);
                    uint4 o;
                    o.x = relu_sum_pk(u1.x, u2.x, ue.x);
                    o.y = relu_sum_pk(u1.y, u2.y, ue.y);
                    o.z = relu_sum_pk(u1.z, u2.z, ue.z);
                    o.w = relu_sum_pk(u1.w, u2.w, ue.w);
                    const bf16x8 a = __builtin_bit_cast(bf16x8, o);
#pragma unroll
                    for (int ni = 0; ni < 4; ++ni)
                        acc[gr][ni] = mfma16(a, b[ni], acc[gr][ni]);
                }
            }
            {   // segment-sum (+bias per edge) into per-graph acc_s
                const float* bias = p ? b2r : b2f;
                float bv[4];
#pragma unroll
                for (int ni = 0; ni < 4; ++ni) bv[ni] = bias[n0 + ni * 16 + li];
#pragma unroll
                for (int gr = 0; gr < 2; ++gr) {
                    const int* targ = p ? fl[gr] : tl[gr];
#pragma unroll
                    for (int r = 0; r < 4; ++r) {
                        const int loc = targ[wm * 16 + quad * 4 + r];
#pragma unroll
                        for (int ni = 0; ni < 4; ++ni)
                            atomicAdd(&acc_s[gr][loc * 132 + n0 + ni * 16 + li],
                                      acc[gr][ni][r] + bv[ni]);
                    }
                }
            }
            __syncthreads();
        }

        {   // upd1: wave w -> cols [w*32,+32); A = [agg | h], both graphs
            const int n0u = w * 32;
            f32x4 ua[2][2][2];
#pragma unroll
            for (int gr = 0; gr < 2; ++gr)
#pragma unroll
                for (int mi = 0; mi < 2; ++mi)
#pragma unroll
                    for (int ni = 0; ni < 2; ++ni) ua[gr][mi][ni] = f32x4{0.f, 0.f, 0.f, 0.f};
            const ushort* pb0 = UW1T + (size_t)(n0u + li) * 256 + quad * 8;
            const ushort* pb1 = UW1T + (size_t)(n0u + 16 + li) * 256 + quad * 8;
#pragma unroll
            for (int kb = 0; kb < 8; ++kb) {
                const bf16x8 b0 = __builtin_bit_cast(bf16x8, *(const uint4*)(pb0 + kb * 32));
                const bf16x8 b1 = __builtin_bit_cast(bf16x8, *(const uint4*)(pb1 + kb * 32));
#pragma unroll
                for (int gr = 0; gr < 2; ++gr) {
                    bf16x8 a[2];
                    if (kb < 4) {
#pragma unroll
                        for (int mi = 0; mi < 2; ++mi) {
                            const int row = mi * 16 + li;
                            const int rr = (row < NPG) ? row : 0;
                            const float* src = &acc_s[gr][rr * 132 + kb * 32 + quad * 8];
                            const float4 f0 = *(const float4*)src;
                            const float4 f1 = *(const float4*)(src + 4);
                            uint4 o;
                            o.x = f2bf2(f0.x, f0.y);
                            o.y = f2bf2(f0.z, f0.w);
                            o.z = f2bf2(f1.x, f1.y);
                            o.w = f2bf2(f1.z, f1.w);
                            a[mi] = __builtin_bit_cast(bf16x8, o);
                        }
                    } else {
                        a[0] = __builtin_bit_cast(bf16x8, ha[gr][0][kb - 4]);
                        a[1] = __builtin_bit_cast(bf16x8, ha[gr][1][kb - 4]);
                    }
#pragma unroll
                    for (int mi = 0; mi < 2; ++mi) {
                        ua[gr][mi][0] = mfma16(a[mi], b0, ua[gr][mi][0]);
                        ua[gr][mi][1] = mfma16(a[mi], b1, ua[gr][mi][1]);
                    }
                }
            }
            const float bv0 = ub1[n0u + li], bv1 = ub1[n0u + 16 + li];
#pragma unroll
            for (int gr = 0; gr < 2; ++gr) {
                ushort* hid = &HPs[gr][0];
#pragma unroll
                for (int mi = 0; mi < 2; ++mi)
#pragma unroll
                    for (int r = 0; r < 4; ++r) {
                        const int row = mi * 16 + quad * 4 + r;
                        if (row < NPG) {
                            hid[row * 264 + n0u + li] = f2bf(fmaxf(ua[gr][mi][0][r] + bv0, 0.f));
                            hid[row * 264 + n0u + 16 + li] = f2bf(fmaxf(ua[gr][mi][1][r] + bv1, 0.f));
                        }
                    }
            }
        }
        __syncthreads();
        {   // upd2: wave w -> cols [w*16,+16); K=256 over hid; hs += , both graphs
            const int n0u = w * 16;
            f32x4 ua[2][2];
#pragma unroll
            for (int gr = 0; gr < 2; ++gr)
#pragma unroll
                for (int mi = 0; mi < 2; ++mi) ua[gr][mi] = f32x4{0.f, 0.f, 0.f, 0.f};
            const ushort* pb0 = UW2T + (size_t)(n0u + li) * 256 + quad * 8;
#pragma unroll
            for (int kb = 0; kb < 8; ++kb) {
                const bf16x8 b0 = __builtin_bit_cast(bf16x8, *(const uint4*)(pb0 + kb * 32));
#pragma unroll
                for (int gr = 0; gr < 2; ++gr) {
                    const ushort* hid = &HPs[gr][0];
#pragma unroll
                    for (int mi = 0; mi < 2; ++mi) {
                        const int row = mi * 16 + li;
                        const int rr = (row < NPG) ? row : 0;
                        const bf16x8 a = __builtin_bit_cast(bf16x8,
                            *(const uint4*)&hid[rr * 264 + kb * 32 + quad * 8]);
                        ua[gr][mi] = mfma16(a, b0, ua[gr][mi]);
                    }
                }
            }
            const float bv = ub2[n0u + li];
#pragma unroll
            for (int gr = 0; gr < 2; ++gr)
#pragma unroll
                for (int mi = 0; mi < 2; ++mi)
#pragma unroll
                    for (int r = 0; r < 4; ++r) {
                        const int row = mi * 16 + quad * 4 + r;
                        if (row < NPG)
                            hs[gr][row * 132 + n0u + li] += ua[gr][mi][r] + bv;
                    }
        }
        __syncthreads();
    }

    // ---- final messages (EMIT): both graphs, acc shared across passes
    {
        uint4 ha[2][2][4];
#pragma unroll
        for (int gr = 0; gr < 2; ++gr)
#pragma unroll
            for (int mi = 0; mi < 2; ++mi) {
                const int row = mi * 16 + li;
                const int rr = (row < NPG) ? row : 0;
#pragma unroll
                for (int kb = 0; kb < 4; ++kb) {
                    const float* src = &hs[gr][rr * 132 + kb * 32 + quad * 8];
                    const float4 f0 = *(const float4*)src;
                    const float4 f1 = *(const float4*)(src + 4);
                    uint4 o;
                    o.x = f2bf2(f0.x, f0.y);
                    o.y = f2bf2(f0.z, f0.w);
                    o.z = f2bf2(f1.x, f1.y);
                    o.w = f2bf2(f1.z, f1.w);
                    ha[gr][mi][kb] = o;
                }
            }
        f32x4 acc[2][4];
#pragma unroll
        for (int gr = 0; gr < 2; ++gr)
#pragma unroll
            for (int j = 0; j < 4; ++j) acc[gr][j] = f32x4{0.f, 0.f, 0.f, 0.f};
        const int n0 = wn * 64;
        const int e = wm * 16 + li;
#pragma unroll 1
        for (int p = 0; p < 2; ++p) {
            {
                const int colw = w * 64;
#pragma unroll
                for (int ni = 0; ni < 4; ++ni) {
                    const int col = colw + ni * 16 + li;
                    const ushort* pb = WhpL + (size_t)(p * 512 + col) * 32 + quad * 8;
                    f32x4 c[2][2];
#pragma unroll
                    for (int gr = 0; gr < 2; ++gr)
#pragma unroll
                        for (int mi = 0; mi < 2; ++mi) c[gr][mi] = f32x4{0.f, 0.f, 0.f, 0.f};
#pragma unroll
                    for (int kb = 0; kb < 4; ++kb) {
                        const bf16x8 b = __builtin_bit_cast(bf16x8,
                            *(const uint4*)(pb + (size_t)kb * 32768));
#pragma unroll
                        for (int gr = 0; gr < 2; ++gr) {
                            c[gr][0] = mfma16(__builtin_bit_cast(bf16x8, ha[gr][0][kb]), b, c[gr][0]);
                            c[gr][1] = mfma16(__builtin_bit_cast(bf16x8, ha[gr][1][kb]), b, c[gr][1]);
                        }
                    }
#pragma unroll
                    for (int gr = 0; gr < 2; ++gr)
#pragma unroll
                        for (int r = 0; r < 4; ++r) {
                            const int r0 = quad * 4 + r;
                            HPs[gr][r0 * 520 + col] = f2bf(c[gr][0][r]);
                            const int r1 = 16 + quad * 4 + r;
                            if (r1 < NPG) HPs[gr][r1 * 520 + col] = f2bf(c[gr][1][r]);
                        }
                }
            }
            __syncthreads();
            const ushort* W2L = p ? W2rL : W2fL;
            const ushort* pb[4];
#pragma unroll
            for (int ni = 0; ni < 4; ++ni)
                pb[ni] = W2L + (size_t)(n0 + ni * 16 + li) * 32 + quad * 8;
#pragma unroll
            for (int kb = 0; kb < 8; ++kb) {
                bf16x8 b[4];
#pragma unroll
                for (int ni = 0; ni < 4; ++ni)
                    b[ni] = __builtin_bit_cast(bf16x8,
                        *(const uint4*)(pb[ni] + (size_t)kb * 4096));
#pragma unroll
                for (int gr = 0; gr < 2; ++gr) {
                    const int i1 = p ? tl[gr][e] : fl[gr][e];
                    const int i2 = p ? fl[gr][e] : tl[gr][e];
                    const uint4 u1 = *(const uint4*)&HPs[gr][i1 * 520 + quad * 8 + kb * 32];
                    const uint4 u2 = *(const uint4*)&HPs[gr][i2 * 520 + 256 + quad * 8 + kb * 32];
                    const uint4 ue = *(const uint4*)(EC2 +
                        (size_t)((2 * g + gr) * 2 + p) * 16384 + e * 32 + quad * 8 + kb * 2048);
                    uint4 o;
                    o.x = relu_sum_pk(u1.x, u2.x, ue.x);
                    o.y = relu_sum_pk(u1.y, u2.y, ue.y);
                    o.z = relu_sum_pk(u1.z, u2.z, ue.z);
                    o.w = relu_sum_pk(u1.w, u2.w, ue.w);
                    const bf16x8 a = __builtin_bit_cast(bf16x8, o);
#pragma unroll
                    for (int ni = 0; ni < 4; ++ni)
                        acc[gr][ni] = mfma16(a, b[ni], acc[gr][ni]);
                }
            }
            __syncthreads();
        }
        float bv[4];
#pragma unroll
        for (int ni = 0; ni < 4; ++ni)
            bv[ni] = b2f[n0 + ni * 16 + li] + b2r[n0 + ni * 16 + li];
#pragma unroll
        for (int gr = 0; gr < 2; ++gr)
#pragma unroll
            for (int r = 0; r < 4; ++r) {
                const int erow = (2 * g + gr) * 64 + wm * 16 + quad * 4 + r;
#pragma unroll
                for (int ni = 0; ni < 4; ++ni)
                    EM[(size_t)erow * 128 + n0 + ni * 16 + li] = acc[gr][ni][r] + bv[ni];
            }
    }
    // write back final h (fp32) for the node head
    for (int u = tid; u < 2 * NPG * 128; u += 512) {
        const int gr = u / (NPG * 128), v = u % (NPG * 128);
        h[((size_t)(2 * g) * NPG * 128) + (size_t)gr * NPG * 128 + v] =
            hs[gr][(v >> 7) * 132 + (v & 127)];
    }
}

// ---------------------------------------------------------------------------
// fp32 tiled GEMM for K=32 encoders (verified core).
// OUT2: also write bf16. ECL: scatter into EC2 fragment layout.
// ---------------------------------------------------------------------------
template<int TM, bool OUTBF, bool OUT2, bool ECL>
__global__ __launch_bounds__(256) void gemm2(
    const float* __restrict__ A, int lda, int K,
    const float* __restrict__ W, int ldw, const float* __restrict__ bias,
    float* __restrict__ C, ushort* __restrict__ Cb, int ldc)
{
    constexpr int BM = TM * 16;
    constexpr int AV = BM / 64;
    __shared__ float As[16][BM + 4];
    __shared__ float Bs[16][132];
    const int tid = threadIdx.x;
    const int m0 = blockIdx.x * BM;
    const int n0 = blockIdx.y * 128;
    const int tx = tid & 15, ty = tid >> 4;
    const int arow = (AV == 2) ? (tid >> 1) : (tid >> 2);
    const int a0   = (AV == 2) ? ((tid & 1) * 8) : ((tid & 3) * 4);
    const int brow = ty;
    const int bcol = tx * 8;
    const int nch = K >> 4;

    float4 aC[2], bC[2], aN[2], bN[2];
    float acc[TM][8];
#pragma unroll
    for (int i = 0; i < TM; ++i)
#pragma unroll
        for (int j = 0; j < 8; ++j) acc[i][j] = 0.f;

    {
        const float* src = A + (size_t)(m0 + arow) * lda + a0;
        aC[0] = *(const float4*)src;
        if (AV == 2) aC[1] = *(const float4*)(src + 4);
        const float* bsrc = W + (size_t)brow * ldw + n0 + bcol;
        bC[0] = *(const float4*)bsrc;
        bC[1] = *(const float4*)(bsrc + 4);
    }

    for (int ch = 0; ch < nch; ++ch) {
        {
            const float* f = (const float*)aC;
#pragma unroll
            for (int i = 0; i < AV * 4; ++i) As[a0 + i][arow] = f[i];
            *(float4*)&Bs[brow][bcol]     = bC[0];
            *(float4*)&Bs[brow][bcol + 4] = bC[1];
        }
        __syncthreads();
        if (ch + 1 < nch) {
            const int kc = (ch + 1) << 4;
            const float* src = A + (size_t)(m0 + arow) * lda + kc + a0;
            aN[0] = *(const float4*)src;
            if (AV == 2) aN[1] = *(const float4*)(src + 4);
            const float* bsrc = W + (size_t)(kc + brow) * ldw + n0 + bcol;
            bN[0] = *(const float4*)bsrc;
            bN[1] = *(const float4*)(bsrc + 4);
        }
#pragma unroll
        for (int kk = 0; kk < 16; ++kk) {
            float afr[TM], bfr[8];
#pragma unroll
            for (int i = 0; i < TM; i += 4)
                *(float4*)&afr[i] = *(const float4*)&As[kk][ty * TM + i];
            *(float4*)&bfr[0] = *(const float4*)&Bs[kk][tx * 8];
            *(float4*)&bfr[4] = *(const float4*)&Bs[kk][tx * 8 + 4];
#pragma unroll
            for (int i = 0; i < TM; ++i)
#pragma unroll
                for (int j = 0; j < 8; ++j) acc[i][j] = fmaf(afr[i], bfr[j], acc[i][j]);
        }
        __syncthreads();
        aC[0] = aN[0]; aC[1] = aN[1];
        bC[0] = bN[0]; bC[1] = bN[1];
    }
#pragma unroll
    for (int i = 0; i < TM; ++i) {
        const int row = m0 + ty * TM + i;
#pragma unroll
        for (int j = 0; j < 8; ++j) {
            const int col = n0 + tx * 8 + j;
            float v = acc[i][j] + bias[col];
            if (ECL) {
                const int gg = row >> 6, eloc = row & 63;
                const int p = col >> 8, kb = (col >> 5) & 7, jj = col & 31;
                Cb[(size_t)(((gg * 2 + p) * 8 + kb)) * 2048 + eloc * 32 + jj] = f2bf(v);
            } else if (OUTBF) {
                Cb[(size_t)row * ldc + col] = f2bf(v);
            } else {
                C[(size_t)row * ldc + col] = v;
                if (OUT2) Cb[(size_t)row * ldc + col] = f2bf(v);
            }
        }
    }
}

// ---------------------------------------------------------------------------
// Weight packing (verified)
// ---------------------------------------------------------------------------
__global__ __launch_bounds__(256) void pack2(
    const float* __restrict__ msg_w1, const float* __restrict__ rmsg_w1,
    const float* __restrict__ msg_b1, const float* __restrict__ rmsg_b1,
    const float* __restrict__ enc_ew, const float* __restrict__ enc_eb,
    const float* __restrict__ msg_w2, const float* __restrict__ rmsg_w2,
    const float* __restrict__ upd_w1, const float* __restrict__ upd_w2,
    float* __restrict__ Wcomb, float* __restrict__ bcomb,
    ushort* __restrict__ WhpL, ushort* __restrict__ W2fL, ushort* __restrict__ W2rL,
    ushort* __restrict__ UW1T, ushort* __restrict__ UW2T)
{
    const int gid = blockIdx.x, tid = threadIdx.x;
    if (gid < 64) {
        const int idx = gid * 256 + tid;
        const int a = idx >> 9, n = idx & 511;
        const float* Wsrc = (n < 256) ? msg_w1 : rmsg_w1;
        const int nc = n & 255;
        float s = 0.f;
        for (int j = 0; j < 128; ++j)
            s = fmaf(enc_ew[a * 128 + j], Wsrc[(256 + j) * 256 + nc], s);
        Wcomb[idx] = s;
    } else if (gid < 66) {
        const int n = (gid - 64) * 256 + tid;
        const float* Wsrc = (n < 256) ? msg_w1 : rmsg_w1;
        const float* bsrc = (n < 256) ? msg_b1 : rmsg_b1;
        const int nc = n & 255;
        float s = bsrc[nc];
        for (int j = 0; j < 128; ++j)
            s = fmaf(enc_eb[j], Wsrc[(256 + j) * 256 + nc], s);
        bcomb[n] = s;
    } else if (gid < 578) {
        const int idx = (gid - 66) * 256 + tid;        // [0,131072)
        const int n = idx >> 7, k = idx & 127;
        const float* Wsrc = (n < 512) ? msg_w1 : rmsg_w1;
        const int part = (n >> 8) & 1, col = n & 255;
        WhpL[(size_t)(k >> 5) * 32768 + n * 32 + (k & 31)] =
            f2bf(Wsrc[(part * 128 + k) * 256 + col]);
    } else if (gid < 706) {
        const int idx = (gid - 578) * 256 + tid;       // [0,32768)
        const int n = idx >> 8, k = idx & 255;
        W2fL[(size_t)(k >> 5) * 4096 + n * 32 + (k & 31)] = f2bf(msg_w2[k * 128 + n]);
    } else if (gid < 834) {
        const int idx = (gid - 706) * 256 + tid;
        const int n = idx >> 8, k = idx & 255;
        W2rL[(size_t)(k >> 5) * 4096 + n * 32 + (k & 31)] = f2bf(rmsg_w2[k * 128 + n]);
    } else if (gid < 1090) {
        const int idx = (gid - 834) * 256 + tid;
        const int n = idx >> 8, k = idx & 255;
        UW1T[idx] = f2bf(upd_w1[k * 256 + n]);
    } else {
        const int idx = (gid - 1090) * 256 + tid;
        const int n = idx >> 8, k = idx & 255;
        UW2T[idx] = f2bf(upd_w2[k * 128 + n]);
    }
}

// ---------------------------------------------------------------------------
// Node head (verified)
// ---------------------------------------------------------------------------
__global__ __launch_bounds__(256) void node_kernel(
    const float* __restrict__ h,
    const float* __restrict__ w1, const float* __restrict__ b1,
    const float* __restrict__ w2, const float* __restrict__ b2,
    const int* __restrict__ qsz, const int* __restrict__ csz,
    float* __restrict__ plan_out, float* __restrict__ loss_out)
{
    __shared__ float qn[32][128];
    __shared__ float cn[32][128];
    __shared__ float t1[32][64];
    __shared__ float mq[32][68];
    __shared__ float mc[32][68];
    __shared__ float la[32][33];
    __shared__ float red[4];
    const int bb = blockIdx.x;
    const int tid = threadIdx.x;
    const int qs = qsz[bb], cs = csz[bb];
    for (int u = tid * 4; u < 4096; u += 1024) {
        const int p = u >> 7, d = u & 127;
        float4 zq = make_float4(0.f, 0.f, 0.f, 0.f), zc = zq;
        if (p < NPG) {
            zq = *(const float4*)(h + (size_t)((2 * bb) * NPG + p) * 128 + d);
            zc = *(const float4*)(h + (size_t)((2 * bb + 1) * NPG + p) * 128 + d);
        }
        *(float4*)&qn[p][d] = zq;
        *(float4*)&cn[p][d] = zc;
    }
    __syncthreads();
    const int col = tid & 63;
    const int rg  = tid >> 6;
    for (int s = 0; s < 2; ++s) {
        const float (*src)[128] = s ? cn : qn;
        float (*dst)[68] = s ? mc : mq;
        const int sz = s ? cs : qs;
        float a8[8];
#pragma unroll
        for (int u = 0; u < 8; ++u) a8[u] = b1[col];
        for (int k = 0; k < 128; ++k) {
            const float wv = w1[k * 64 + col];
#pragma unroll
            for (int u = 0; u < 8; ++u) a8[u] = fmaf(src[rg + 4 * u][k], wv, a8[u]);
        }
#pragma unroll
        for (int u = 0; u < 8; ++u) t1[rg + 4 * u][col] = fmaxf(a8[u], 0.f);
        __syncthreads();
#pragma unroll
        for (int u = 0; u < 8; ++u) a8[u] = b2[col];
        for (int k = 0; k < 64; ++k) {
            const float wv = w2[k * 64 + col];
#pragma unroll
            for (int u = 0; u < 8; ++u) a8[u] = fmaf(t1[rg + 4 * u][k], wv, a8[u]);
        }
#pragma unroll
        for (int u = 0; u < 8; ++u) {
            const int r = rg + 4 * u;
            dst[r][col] = (r < sz) ? a8[u] : 0.f;
        }
        __syncthreads();
    }
    {
        const int q = tid >> 3, cg = tid & 7;
#pragma unroll
        for (int u = 0; u < 4; ++u) {
            const int c = cg + 8 * u;
            float s = 0.f;
            for (int d = 0; d < 64; ++d) s = fmaf(mq[q][d], mc[c][d], s);
            la[q][c] = s * TEMPINV;
        }
    }
    __syncthreads();
    const int l8 = tid & 7, rq = tid >> 3;
    for (int it = 0; it < SINK_ITERS; ++it) {
        {
            float x[4];
#pragma unroll
            for (int u = 0; u < 4; ++u) x[u] = la[rq][l8 * 4 + u];
            float m = fmaxf(fmaxf(x[0], x[1]), fmaxf(x[2], x[3]));
            m = fmaxf(m, __shfl_xor(m, 1));
            m = fmaxf(m, __shfl_xor(m, 2));
            m = fmaxf(m, __shfl_xor(m, 4));
            float s = __expf(x[0] - m) + __expf(x[1] - m) + __expf(x[2] - m) + __expf(x[3] - m);
            s += __shfl_xor(s, 1);
            s += __shfl_xor(s, 2);
            s += __shfl_xor(s, 4);
            const float lse = m + __logf(s);
#pragma unroll
            for (int u = 0; u < 4; ++u) la[rq][l8 * 4 + u] = x[u] - lse;
        }
        __syncthreads();
        {
            float x[4];
#pragma unroll
            for (int u = 0; u < 4; ++u) x[u] = la[l8 * 4 + u][rq];
            float m = fmaxf(fmaxf(x[0], x[1]), fmaxf(x[2], x[3]));
            m = fmaxf(m, __shfl_xor(m, 1));
            m = fmaxf(m, __shfl_xor(m, 2));
            m = fmaxf(m, __shfl_xor(m, 4));
            float s = __expf(x[0] - m) + __expf(x[1] - m) + __expf(x[2] - m) + __expf(x[3] - m);
            s += __shfl_xor(s, 1);
            s += __shfl_xor(s, 2);
            s += __shfl_xor(s, 4);
            const float lse = m + __logf(s);
#pragma unroll
            for (int u = 0; u < 4; ++u) la[l8 * 4 + u][rq] = x[u] - lse;
        }
        __syncthreads();
    }
    for (int u = tid; u < 1024; u += 256) {
        const int q = u >> 5, c = u & 31;
        const float p = __expf(la[q][c]);
        la[q][c] = p;
        plan_out[(size_t)bb * 1024 + u] = p;
    }
    __syncthreads();
    float lsum = 0.f;
    {
        const int q = tid >> 3, dg = tid & 7;
        for (int u = 0; u < 16; ++u) {
            const int d = dg + 8 * u;
            float pc = 0.f;
#pragma unroll
            for (int c = 0; c < 32; ++c) pc = fmaf(la[q][c], cn[c][d], pc);
            lsum += fmaxf(qn[q][d] - pc, 0.f);
        }
    }
#pragma unroll
    for (int off = 1; off < 64; off <<= 1) lsum += __shfl_xor(lsum, off);
    if ((tid & 63) == 0) red[tid >> 6] = lsum;
    __syncthreads();
    if (tid == 0) loss_out[bb] = -(red[0] + red[1] + red[2] + red[3]);
}

// ---------------------------------------------------------------------------
// Edge head (verified)
// ---------------------------------------------------------------------------
__global__ __launch_bounds__(256) void edge_kernel(
    const float* __restrict__ plan, const float* __restrict__ EM,
    const int* __restrict__ from_idx, const int* __restrict__ to_idx,
    float* __restrict__ loss_out)
{
    __shared__ float T[32][33];
    __shared__ float la[64][65];
    __shared__ float ce[64][128];
    __shared__ int qf[64], qt[64], cfi[64], cti[64];
    __shared__ float red[4];
    const int bb = blockIdx.x;
    const int tid = threadIdx.x;
    for (int u = tid; u < 1024; u += 256) T[u >> 5][u & 31] = plan[(size_t)bb * 1024 + u];
    if (tid < 64) {
        const int gq = 2 * bb, gc = 2 * bb + 1;
        qf[tid]  = from_idx[gq * 64 + tid] - gq * NPG;
        qt[tid]  = to_idx  [gq * 64 + tid] - gq * NPG;
        cfi[tid] = from_idx[gc * 64 + tid] - gc * NPG;
        cti[tid] = to_idx  [gc * 64 + tid] - gc * NPG;
    }
    {
        const int gc = 2 * bb + 1;
        for (int u = tid * 4; u < 8192; u += 1024) {
            const int i = u >> 7, d = u & 127;
            *(float4*)&ce[i][d] = *(const float4*)(EM + (size_t)(gc * 64 + i) * 128 + d);
        }
    }
    __syncthreads();
    {
        const int i = tid >> 2, jg = tid & 3;
        const int a = qf[i], b_ = qt[i];
#pragma unroll
        for (int u = 0; u < 16; ++u) {
            const int j = jg * 16 + u;
            const float s = T[a][cfi[j]] * T[b_][cti[j]] + T[a][cti[j]] * T[b_][cfi[j]];
            la[i][j] = s * TEMPINV;
        }
    }
    __syncthreads();
    const int l4 = tid & 3, rr = tid >> 2;
    for (int it = 0; it < SINK_ITERS; ++it) {
        {
            float x[16];
#pragma unroll
            for (int u = 0; u < 16; ++u) x[u] = la[rr][l4 * 16 + u];
            float m = x[0];
#pragma unroll
            for (int u = 1; u < 16; ++u) m = fmaxf(m, x[u]);
            m = fmaxf(m, __shfl_xor(m, 1));
            m = fmaxf(m, __shfl_xor(m, 2));
            float s = 0.f;
#pragma unroll
            for (int u = 0; u < 16; ++u) s += __expf(x[u] - m);
            s += __shfl_xor(s, 1);
            s += __shfl_xor(s, 2);
            const float lse = m + __logf(s);
#pragma unroll
            for (int u = 0; u < 16; ++u) la[rr][l4 * 16 + u] = x[u] - lse;
        }
        __syncthreads();
        {
            float x[16];
#pragma unroll
            for (int u = 0; u < 16; ++u) x[u] = la[l4 * 16 + u][rr];
            float m = x[0];
#pragma unroll
            for (int u = 1; u < 16; ++u) m = fmaxf(m, x[u]);
            m = fmaxf(m, __shfl_xor(m, 1));
            m = fmaxf(m, __shfl_xor(m, 2));
            float s = 0.f;
#pragma unroll
            for (int u = 0; u < 16; ++u) s += __expf(x[u] - m);
            s += __shfl_xor(s, 1);
            s += __shfl_xor(s, 2);
            const float lse = m + __logf(s);
#pragma unroll
            for (int u = 0; u < 16; ++u) la[l4 * 16 + u][rr] = x[u] - lse;
        }
        __syncthreads();
    }
    for (int u = tid; u < 4096; u += 256) la[u >> 6][u & 63] = __expf(la[u >> 6][u & 63]);
    __syncthreads();
    float lsum = 0.f;
    {
        const int q = tid >> 2, dg = tid & 3;
        const float* qe = EM + (size_t)((2 * bb) * 64 + q) * 128;
        for (int u = 0; u < 32; ++u) {
            const int d = dg + 4 * u;
            float pc = 0.f;
            for (int c = 0; c < 64; ++c) pc = fmaf(la[q][c], ce[c][d], pc);
            lsum += fmaxf(qe[d] - pc, 0.f);
        }
    }
#pragma unroll
    for (int off = 1; off < 64; off <<= 1) lsum += __shfl_xor(lsum, off);
    if ((tid & 63) == 0) red[tid >> 6] = lsum;
    __syncthreads();
    if (tid == 0) loss_out[bb] -= CW * (red[0] + red[1] + red[2] + red[3]);
}

// ---------------------------------------------------------------------------
extern "C" void kernel_launch(void* const* d_in, const int* in_sizes, int n_in,
                              void* d_out, int out_size, void* d_ws, size_t ws_size,
                              hipStream_t stream)
{
    const float* node_features = (const float*)d_in[0];
    const float* edge_features = (const float*)d_in[1];
    const float* enc_nw  = (const float*)d_in[2];
    const float* enc_nb  = (const float*)d_in[3];
    const float* enc_ew  = (const float*)d_in[4];
    const float* enc_eb  = (const float*)d_in[5];
    const float* msg_w1  = (const float*)d_in[6];
    const float* msg_b1  = (const float*)d_in[7];
    const float* msg_w2  = (const float*)d_in[8];
    const float* msg_b2  = (const float*)d_in[9];
    const float* rmsg_w1 = (const float*)d_in[10];
    const float* rmsg_b1 = (const float*)d_in[11];
    const float* rmsg_w2 = (const float*)d_in[12];
    const float* rmsg_b2 = (const float*)d_in[13];
    const float* upd_w1  = (const float*)d_in[14];
    const float* upd_b1  = (const float*)d_in[15];
    const float* upd_w2  = (const float*)d_in[16];
    const float* upd_b2  = (const float*)d_in[17];
    const float* sk_w1   = (const float*)d_in[18];
    const float* sk_b1   = (const float*)d_in[19];
    const float* sk_w2   = (const float*)d_in[20];
    const float* sk_b2   = (const float*)d_in[21];
    const int* from_idx  = (const int*)d_in[22];
    const int* to_idx    = (const int*)d_in[23];
    const int* qsizes    = (const int*)d_in[24];
    const int* csizes    = (const int*)d_in[25];
    float* out = (float*)d_out;

    float* ws    = (float*)d_ws;
    float* h     = ws;                          // NN*128 fp32
    float* EM    = h + (size_t)NN * 128;        // NE*128 fp32
    float* plan  = EM + (size_t)NE * 128;       // NB*1024
    float* Wcomb = plan + (size_t)NB * 1024;    // 32*512
    float* bcomb = Wcomb + 16384;               // 512
    ushort* EC2  = (ushort*)(bcomb + 512);      // NE*512
    ushort* WhpL = EC2 + (size_t)NE * 512;      // 131072
    ushort* W2fL = WhpL + 131072;               // 32768
    ushort* W2rL = W2fL + 32768;                // 32768
    ushort* UW1T = W2rL + 32768;                // 65536
    ushort* UW2T = UW1T + 65536;                // 32768

    const dim3 blk(256);
    const dim3 blk512(512);

    pack2<<<1218, blk, 0, stream>>>(msg_w1, rmsg_w1, msg_b1, rmsg_b1,
                                    enc_ew, enc_eb, msg_w2, rmsg_w2, upd_w1, upd_w2,
                                    Wcomb, bcomb, WhpL, W2fL, W2rL, UW1T, UW2T);
    // node encoder: h fp32
    gemm2<4, false, false, false><<<dim3(NN / 64, 1), blk, 0, stream>>>(
        node_features, 32, 32, enc_nw, 128, enc_nb, h, nullptr, 128);
    // edge encoder folded with msg layer-1 edge slice -> EC2 fragment layout
    gemm2<8, false, false, true><<<dim3(NE / 128, 4), blk, 0, stream>>>(
        edge_features, 32, 32, Wcomb, 512, bcomb, nullptr, EC2, 512);

    // all 3 GNN steps + final messages; one block = two graphs
    gnn_fused<<<dim3(NG / 2), blk512, 0, stream>>>(
        h, EC2, WhpL, W2fL, W2rL, msg_b2, rmsg_b2,
        UW1T, upd_b1, UW2T, upd_b2, from_idx, to_idx, EM);

    node_kernel<<<NB, blk, 0, stream>>>(
        h, sk_w1, sk_b1, sk_w2, sk_b2, qsizes, csizes, plan, out);
    edge_kernel<<<NB, blk, 0, stream>>>(
        plan, EM, from_idx, to_idx, out);
}

// Round 12
// 468.445 us; speedup vs baseline: 1.3184x; 1.1544x over previous
//
#include <hip/hip_runtime.h>
#include <math.h>

#define NPG 28
#define EPG 64
#define NB  256
#define NG  512
#define NN  14336
#define NE  32768
#define TEMPINV 10.0f
#define SINK_ITERS 20
#define CW 0.9f

typedef unsigned int uint;
typedef unsigned short ushort;
typedef __attribute__((ext_vector_type(8))) __bf16 bf16x8;
typedef __attribute__((ext_vector_type(4))) float f32x4;

__device__ __forceinline__ ushort f2bf(float x) {
    uint u = __float_as_uint(x);
    u += 0x7fffu + ((u >> 16) & 1u);
    return (ushort)(u >> 16);
}
__device__ __forceinline__ uint f2bf2(float lo, float hi) {
    return (uint)f2bf(lo) | ((uint)f2bf(hi) << 16);
}
__device__ __forceinline__ float bflo(uint w) { return __uint_as_float(w << 16); }
__device__ __forceinline__ float bfhi(uint w) { return __uint_as_float(w & 0xffff0000u); }
__device__ __forceinline__ uint relu_sum_pk(uint w1, uint w2, uint w3) {
    float lo = fmaxf(bflo(w1) + bflo(w2) + bflo(w3), 0.f);
    float hi = fmaxf(bfhi(w1) + bfhi(w2) + bfhi(w3), 0.f);
    return f2bf2(lo, hi);
}
__device__ __forceinline__ uint4 pack_f32x8(const float* src) {
    const float4 f0 = *(const float4*)src;
    const float4 f1 = *(const float4*)(src + 4);
    uint4 o;
    o.x = f2bf2(f0.x, f0.y);
    o.y = f2bf2(f0.z, f0.w);
    o.z = f2bf2(f1.x, f1.y);
    o.w = f2bf2(f1.z, f1.w);
    return o;
}
__device__ __forceinline__ f32x4 mfma16(bf16x8 a, bf16x8 b, f32x4 c) {
    return __builtin_amdgcn_mfma_f32_16x16x32_bf16(a, b, c, 0, 0, 0);
}

// ---------------------------------------------------------------------------
// Mega-fused GNN kernel v3: one block = one graph, 512 threads (8 waves).
// NEW: node-encoder (h = nf@enc_nw) and EC (= ef@Wcomb) computed IN-BLOCK
// into LDS, so the step loop touches HBM only for nf/ef/weights (~12 MB
// total) — kills the 900-cyc EC2 HBM-miss chains that bounded rounds 10/11.
// LDS: HPs 29.1K (alias hid) + acc_s 14.8K + hs 14.8K + ECs 64K = 122.7 KB.
// ---------------------------------------------------------------------------
__global__ __launch_bounds__(512) void gnn_fused(
    const float* __restrict__ nf, const float* __restrict__ ef,
    const ushort* __restrict__ encL, const float* __restrict__ enc_nb,
    const ushort* __restrict__ WcombL, const float* __restrict__ bcomb,
    const ushort* __restrict__ WhpL,
    const ushort* __restrict__ W2fL, const ushort* __restrict__ W2rL,
    const float* __restrict__ b2f, const float* __restrict__ b2r,
    const ushort* __restrict__ UW1T, const float* __restrict__ ub1,
    const ushort* __restrict__ UW2T, const float* __restrict__ ub2,
    const int* __restrict__ from_idx, const int* __restrict__ to_idx,
    float* __restrict__ h, float* __restrict__ EM)
{
    __shared__ ushort HPs[NPG * 520];     // pass-half 28x512; alias hid 28x264
    __shared__ ushort ECs[2 * 8 * 2048];  // [p][kb][e*32+j] bf16, 64 KB
    __shared__ float acc_s[NPG * 132];
    __shared__ float hs[NPG * 132];
    __shared__ int fl[64], tl[64];
    const int g = blockIdx.x;
    const int tid = threadIdx.x;
    const int w = tid >> 6, lane = tid & 63;
    const int li = lane & 15, quad = lane >> 4;
    const int wm = w >> 1, wn = w & 1;
    ushort* hid = &HPs[0];

    if (tid < 64) {
        fl[tid] = from_idx[g * 64 + tid] - g * NPG;
        tl[tid] = to_idx[g * 64 + tid] - g * NPG;
    }

    {   // ---- node encoder: hs = nf @ enc_nw + enc_nb (K=32, 1 kb)
        uint4 anf[2];
#pragma unroll
        for (int mi = 0; mi < 2; ++mi) {
            const int row = mi * 16 + li;
            const int rr = (row < NPG) ? row : 0;
            const float4 f0 = *(const float4*)(nf + ((size_t)g * NPG + rr) * 32 + quad * 8);
            const float4 f1 = *(const float4*)(nf + ((size_t)g * NPG + rr) * 32 + quad * 8 + 4);
            uint4 o;
            o.x = f2bf2(f0.x, f0.y); o.y = f2bf2(f0.z, f0.w);
            o.z = f2bf2(f1.x, f1.y); o.w = f2bf2(f1.z, f1.w);
            anf[mi] = o;
        }
        const int col = w * 16 + li;                 // 8 waves x 16 = 128 cols
        const bf16x8 b = __builtin_bit_cast(bf16x8,
            *(const uint4*)(encL + (size_t)col * 32 + quad * 8));
        f32x4 c0 = mfma16(__builtin_bit_cast(bf16x8, anf[0]), b, f32x4{0.f, 0.f, 0.f, 0.f});
        f32x4 c1 = mfma16(__builtin_bit_cast(bf16x8, anf[1]), b, f32x4{0.f, 0.f, 0.f, 0.f});
        const float bv = enc_nb[col];
#pragma unroll
        for (int r = 0; r < 4; ++r) {
            const int r0 = quad * 4 + r;
            hs[r0 * 132 + col] = c0[r] + bv;
            const int r1 = 16 + quad * 4 + r;
            if (r1 < NPG) hs[r1 * 132 + col] = c1[r] + bv;
        }
    }
    {   // ---- edge contribution: ECs = ef @ Wcomb + bcomb (K=32), in LDS
        uint4 aef[4];
#pragma unroll
        for (int mi = 0; mi < 4; ++mi) {
            const int e = mi * 16 + li;
            const float4 f0 = *(const float4*)(ef + ((size_t)g * 64 + e) * 32 + quad * 8);
            const float4 f1 = *(const float4*)(ef + ((size_t)g * 64 + e) * 32 + quad * 8 + 4);
            uint4 o;
            o.x = f2bf2(f0.x, f0.y); o.y = f2bf2(f0.z, f0.w);
            o.z = f2bf2(f1.x, f1.y); o.w = f2bf2(f1.z, f1.w);
            aef[mi] = o;
        }
#pragma unroll
        for (int ni = 0; ni < 4; ++ni) {
            const int col = w * 64 + ni * 16 + li;   // 8 waves x 64 = 512 cols
            const bf16x8 b = __builtin_bit_cast(bf16x8,
                *(const uint4*)(WcombL + (size_t)col * 32 + quad * 8));
            const float bv = bcomb[col];
            const int pp = col >> 8, kbl = (col >> 5) & 7, j = col & 31;
#pragma unroll
            for (int mi = 0; mi < 4; ++mi) {
                f32x4 c = mfma16(__builtin_bit_cast(bf16x8, aef[mi]), b,
                                 f32x4{0.f, 0.f, 0.f, 0.f});
#pragma unroll
                for (int r = 0; r < 4; ++r) {
                    const int e = mi * 16 + quad * 4 + r;
                    ECs[pp * 16384 + kbl * 2048 + e * 32 + j] = f2bf(c[r] + bv);
                }
            }
        }
    }
    __syncthreads();

#pragma unroll 1
    for (int step = 0; step < 3; ++step) {
        // bf16 A-frags of current h
        uint4 ha[2][4];
#pragma unroll
        for (int mi = 0; mi < 2; ++mi) {
            const int row = mi * 16 + li;
            const int rr = (row < NPG) ? row : 0;
#pragma unroll
            for (int kb = 0; kb < 4; ++kb)
                ha[mi][kb] = pack_f32x8(&hs[rr * 132 + kb * 32 + quad * 8]);
        }
        for (int u = tid; u < NPG * 132; u += 512) acc_s[u] = 0.f;

        f32x4 acc[4];
#pragma unroll
        for (int j = 0; j < 4; ++j) acc[j] = f32x4{0.f, 0.f, 0.f, 0.f};

#pragma unroll 1
        for (int p = 0; p < 2; ++p) {
            {   // HP pass-half: wave w -> local cols [w*64, w*64+64)
                const int colw = w * 64;
#pragma unroll
                for (int ni = 0; ni < 4; ++ni) {
                    const int col = colw + ni * 16 + li;
                    const ushort* pb = WhpL + (size_t)(p * 512 + col) * 32 + quad * 8;
                    f32x4 c0 = f32x4{0.f, 0.f, 0.f, 0.f};
                    f32x4 c1 = f32x4{0.f, 0.f, 0.f, 0.f};
#pragma unroll
                    for (int kb = 0; kb < 4; ++kb) {
                        const bf16x8 b = __builtin_bit_cast(bf16x8,
                            *(const uint4*)(pb + (size_t)kb * 32768));
                        c0 = mfma16(__builtin_bit_cast(bf16x8, ha[0][kb]), b, c0);
                        c1 = mfma16(__builtin_bit_cast(bf16x8, ha[1][kb]), b, c1);
                    }
#pragma unroll
                    for (int r = 0; r < 4; ++r) {
                        const int r0 = quad * 4 + r;
                        HPs[r0 * 520 + col] = f2bf(c0[r]);
                        const int r1 = 16 + quad * 4 + r;
                        if (r1 < NPG) HPs[r1 * 520 + col] = f2bf(c1[r]);
                    }
                }
            }
            __syncthreads();

            if (p == 1) {
#pragma unroll
                for (int j = 0; j < 4; ++j) acc[j] = f32x4{0.f, 0.f, 0.f, 0.f};
            }
            // layer-2: wave (wm,wn): edges [wm*16,+16), cols [wn*64,+64)
            const int e = wm * 16 + li;
            const int i1 = p ? tl[e] : fl[e];
            const int i2 = p ? fl[e] : tl[e];
            const int ad1 = i1 * 520 + quad * 8;
            const int ad2 = i2 * 520 + 256 + quad * 8;
            const int ade = p * 16384 + e * 32 + quad * 8;
            const ushort* W2L = p ? W2rL : W2fL;
            const int n0 = wn * 64;
            const ushort* pb[4];
#pragma unroll
            for (int ni = 0; ni < 4; ++ni)
                pb[ni] = W2L + (size_t)(n0 + ni * 16 + li) * 32 + quad * 8;
#pragma unroll
            for (int kb = 0; kb < 8; ++kb) {
                const uint4 u1 = *(const uint4*)&HPs[ad1 + kb * 32];
                const uint4 u2 = *(const uint4*)&HPs[ad2 + kb * 32];
                const uint4 ue = *(const uint4*)&ECs[ade + kb * 2048];
                uint4 o;
                o.x = relu_sum_pk(u1.x, u2.x, ue.x);
                o.y = relu_sum_pk(u1.y, u2.y, ue.y);
                o.z = relu_sum_pk(u1.z, u2.z, ue.z);
                o.w = relu_sum_pk(u1.w, u2.w, ue.w);
                const bf16x8 a = __builtin_bit_cast(bf16x8, o);
#pragma unroll
                for (int ni = 0; ni < 4; ++ni) {
                    const bf16x8 b = __builtin_bit_cast(bf16x8,
                        *(const uint4*)(pb[ni] + (size_t)kb * 4096));
                    acc[ni] = mfma16(a, b, acc[ni]);
                }
            }
            {   // segment-sum (+bias per edge) into acc_s
                const int* targ = p ? fl : tl;
                const float* bias = p ? b2r : b2f;
                float bv[4];
#pragma unroll
                for (int ni = 0; ni < 4; ++ni) bv[ni] = bias[n0 + ni * 16 + li];
#pragma unroll
                for (int r = 0; r < 4; ++r) {
                    const int loc = targ[wm * 16 + quad * 4 + r];
#pragma unroll
                    for (int ni = 0; ni < 4; ++ni)
                        atomicAdd(&acc_s[loc * 132 + n0 + ni * 16 + li],
                                  acc[ni][r] + bv[ni]);
                }
            }
            __syncthreads();
        }

        {   // upd1: wave w -> cols [w*32,+32); A = [agg | h] (K=256)
            const int n0u = w * 32;
            f32x4 ua[2][2];
#pragma unroll
            for (int mi = 0; mi < 2; ++mi)
#pragma unroll
                for (int ni = 0; ni < 2; ++ni) ua[mi][ni] = f32x4{0.f, 0.f, 0.f, 0.f};
            const ushort* pb0 = UW1T + (size_t)(n0u + li) * 256 + quad * 8;
            const ushort* pb1 = UW1T + (size_t)(n0u + 16 + li) * 256 + quad * 8;
#pragma unroll
            for (int kb = 0; kb < 8; ++kb) {
                bf16x8 a[2];
                if (kb < 4) {
#pragma unroll
                    for (int mi = 0; mi < 2; ++mi) {
                        const int row = mi * 16 + li;
                        const int rr = (row < NPG) ? row : 0;
                        a[mi] = __builtin_bit_cast(bf16x8,
                            pack_f32x8(&acc_s[rr * 132 + kb * 32 + quad * 8]));
                    }
                } else {
                    a[0] = __builtin_bit_cast(bf16x8, ha[0][kb - 4]);
                    a[1] = __builtin_bit_cast(bf16x8, ha[1][kb - 4]);
                }
                const bf16x8 b0 = __builtin_bit_cast(bf16x8, *(const uint4*)(pb0 + kb * 32));
                const bf16x8 b1 = __builtin_bit_cast(bf16x8, *(const uint4*)(pb1 + kb * 32));
#pragma unroll
                for (int mi = 0; mi < 2; ++mi) {
                    ua[mi][0] = mfma16(a[mi], b0, ua[mi][0]);
                    ua[mi][1] = mfma16(a[mi], b1, ua[mi][1]);
                }
            }
            const float bv0 = ub1[n0u + li], bv1 = ub1[n0u + 16 + li];
#pragma unroll
            for (int mi = 0; mi < 2; ++mi)
#pragma unroll
                for (int r = 0; r < 4; ++r) {
                    const int row = mi * 16 + quad * 4 + r;
                    if (row < NPG) {
                        hid[row * 264 + n0u + li] = f2bf(fmaxf(ua[mi][0][r] + bv0, 0.f));
                        hid[row * 264 + n0u + 16 + li] = f2bf(fmaxf(ua[mi][1][r] + bv1, 0.f));
                    }
                }
        }
        __syncthreads();
        {   // upd2: wave w -> cols [w*16,+16); K=256 over hid; hs +=
            const int n0u = w * 16;
            f32x4 ua[2];
            ua[0] = f32x4{0.f, 0.f, 0.f, 0.f};
            ua[1] = f32x4{0.f, 0.f, 0.f, 0.f};
            const ushort* pb0 = UW2T + (size_t)(n0u + li) * 256 + quad * 8;
#pragma unroll
            for (int kb = 0; kb < 8; ++kb) {
                bf16x8 a[2];
#pragma unroll
                for (int mi = 0; mi < 2; ++mi) {
                    const int row = mi * 16 + li;
                    const int rr = (row < NPG) ? row : 0;
                    a[mi] = __builtin_bit_cast(bf16x8,
                        *(const uint4*)&hid[rr * 264 + kb * 32 + quad * 8]);
                }
                const bf16x8 b0 = __builtin_bit_cast(bf16x8, *(const uint4*)(pb0 + kb * 32));
                ua[0] = mfma16(a[0], b0, ua[0]);
                ua[1] = mfma16(a[1], b0, ua[1]);
            }
            const float bv = ub2[n0u + li];
#pragma unroll
            for (int mi = 0; mi < 2; ++mi)
#pragma unroll
                for (int r = 0; r < 4; ++r) {
                    const int row = mi * 16 + quad * 4 + r;
                    if (row < NPG)
                        hs[row * 132 + n0u + li] += ua[mi][r] + bv;
                }
        }
        __syncthreads();
    }

    // ---- final messages (EMIT): acc shared across passes -> EM fp32
    {
        uint4 ha[2][4];
#pragma unroll
        for (int mi = 0; mi < 2; ++mi) {
            const int row = mi * 16 + li;
            const int rr = (row < NPG) ? row : 0;
#pragma unroll
            for (int kb = 0; kb < 4; ++kb)
                ha[mi][kb] = pack_f32x8(&hs[rr * 132 + kb * 32 + quad * 8]);
        }
        f32x4 acc[4];
#pragma unroll
        for (int j = 0; j < 4; ++j) acc[j] = f32x4{0.f, 0.f, 0.f, 0.f};
        const int n0 = wn * 64;
#pragma unroll 1
        for (int p = 0; p < 2; ++p) {
            {
                const int colw = w * 64;
#pragma unroll
                for (int ni = 0; ni < 4; ++ni) {
                    const int col = colw + ni * 16 + li;
                    const ushort* pb = WhpL + (size_t)(p * 512 + col) * 32 + quad * 8;
                    f32x4 c0 = f32x4{0.f, 0.f, 0.f, 0.f};
                    f32x4 c1 = f32x4{0.f, 0.f, 0.f, 0.f};
#pragma unroll
                    for (int kb = 0; kb < 4; ++kb) {
                        const bf16x8 b = __builtin_bit_cast(bf16x8,
                            *(const uint4*)(pb + (size_t)kb * 32768));
                        c0 = mfma16(__builtin_bit_cast(bf16x8, ha[0][kb]), b, c0);
                        c1 = mfma16(__builtin_bit_cast(bf16x8, ha[1][kb]), b, c1);
                    }
#pragma unroll
                    for (int r = 0; r < 4; ++r) {
                        const int r0 = quad * 4 + r;
                        HPs[r0 * 520 + col] = f2bf(c0[r]);
                        const int r1 = 16 + quad * 4 + r;
                        if (r1 < NPG) HPs[r1 * 520 + col] = f2bf(c1[r]);
                    }
                }
            }
            __syncthreads();
            const int e = wm * 16 + li;
            const int i1 = p ? tl[e] : fl[e];
            const int i2 = p ? fl[e] : tl[e];
            const int ad1 = i1 * 520 + quad * 8;
            const int ad2 = i2 * 520 + 256 + quad * 8;
            const int ade = p * 16384 + e * 32 + quad * 8;
            const ushort* W2L = p ? W2rL : W2fL;
            const ushort* pb[4];
#pragma unroll
            for (int ni = 0; ni < 4; ++ni)
                pb[ni] = W2L + (size_t)(n0 + ni * 16 + li) * 32 + quad * 8;
#pragma unroll
            for (int kb = 0; kb < 8; ++kb) {
                const uint4 u1 = *(const uint4*)&HPs[ad1 + kb * 32];
                const uint4 u2 = *(const uint4*)&HPs[ad2 + kb * 32];
                const uint4 ue = *(const uint4*)&ECs[ade + kb * 2048];
                uint4 o;
                o.x = relu_sum_pk(u1.x, u2.x, ue.x);
                o.y = relu_sum_pk(u1.y, u2.y, ue.y);
                o.z = relu_sum_pk(u1.z, u2.z, ue.z);
                o.w = relu_sum_pk(u1.w, u2.w, ue.w);
                const bf16x8 a = __builtin_bit_cast(bf16x8, o);
#pragma unroll
                for (int ni = 0; ni < 4; ++ni) {
                    const bf16x8 b = __builtin_bit_cast(bf16x8,
                        *(const uint4*)(pb[ni] + (size_t)kb * 4096));
                    acc[ni] = mfma16(a, b, acc[ni]);
                }
            }
            __syncthreads();
        }
        float bv[4];
#pragma unroll
        for (int ni = 0; ni < 4; ++ni)
            bv[ni] = b2f[n0 + ni * 16 + li] + b2r[n0 + ni * 16 + li];
#pragma unroll
        for (int r = 0; r < 4; ++r) {
            const int erow = g * 64 + wm * 16 + quad * 4 + r;
#pragma unroll
            for (int ni = 0; ni < 4; ++ni)
                EM[(size_t)erow * 128 + n0 + ni * 16 + li] = acc[ni][r] + bv[ni];
        }
    }
    // write back final h (fp32) for the node head
    for (int u = tid; u < NPG * 128; u += 512)
        h[(size_t)g * (NPG * 128) + u] = hs[(u >> 7) * 132 + (u & 127)];
}

// ---------------------------------------------------------------------------
// Weight packing: WcombL (bf16 n x k), enc_nwL, WhpL, W2fL/W2rL, UW1T/UW2T.
// ---------------------------------------------------------------------------
__global__ __launch_bounds__(256) void pack2(
    const float* __restrict__ msg_w1, const float* __restrict__ rmsg_w1,
    const float* __restrict__ msg_b1, const float* __restrict__ rmsg_b1,
    const float* __restrict__ enc_ew, const float* __restrict__ enc_eb,
    const float* __restrict__ enc_nw,
    const float* __restrict__ msg_w2, const float* __restrict__ rmsg_w2,
    const float* __restrict__ upd_w1, const float* __restrict__ upd_w2,
    ushort* __restrict__ WcombL, float* __restrict__ bcomb,
    ushort* __restrict__ encL,
    ushort* __restrict__ WhpL, ushort* __restrict__ W2fL, ushort* __restrict__ W2rL,
    ushort* __restrict__ UW1T, ushort* __restrict__ UW2T)
{
    const int gid = blockIdx.x, tid = threadIdx.x;
    if (gid < 64) {                        // WcombL: [n=512][k=32] bf16
        const int idx = gid * 256 + tid;
        const int a = idx >> 9, n = idx & 511;
        const float* Wsrc = (n < 256) ? msg_w1 : rmsg_w1;
        const int nc = n & 255;
        float s = 0.f;
        for (int j = 0; j < 128; ++j)
            s = fmaf(enc_ew[a * 128 + j], Wsrc[(256 + j) * 256 + nc], s);
        WcombL[n * 32 + a] = f2bf(s);
    } else if (gid < 66) {                 // bcomb: 512 fp32
        const int n = (gid - 64) * 256 + tid;
        const float* Wsrc = (n < 256) ? msg_w1 : rmsg_w1;
        const float* bsrc = (n < 256) ? msg_b1 : rmsg_b1;
        const int nc = n & 255;
        float s = bsrc[nc];
        for (int j = 0; j < 128; ++j)
            s = fmaf(enc_eb[j], Wsrc[(256 + j) * 256 + nc], s);
        bcomb[n] = s;
    } else if (gid < 82) {                 // encL: [n=128][k=32] bf16
        const int idx = (gid - 66) * 256 + tid;     // [0,4096)
        const int n = idx >> 5, k = idx & 31;
        encL[idx] = f2bf(enc_nw[k * 128 + n]);
    } else if (gid < 594) {                // WhpL: [(k>>5)][n=1024][k&31]
        const int idx = (gid - 82) * 256 + tid;     // [0,131072)
        const int n = idx >> 7, k = idx & 127;
        const float* Wsrc = (n < 512) ? msg_w1 : rmsg_w1;
        const int part = (n >> 8) & 1, col = n & 255;
        WhpL[(size_t)(k >> 5) * 32768 + n * 32 + (k & 31)] =
            f2bf(Wsrc[(part * 128 + k) * 256 + col]);
    } else if (gid < 722) {                // W2fL
        const int idx = (gid - 594) * 256 + tid;    // [0,32768)
        const int n = idx >> 8, k = idx & 255;
        W2fL[(size_t)(k >> 5) * 4096 + n * 32 + (k & 31)] = f2bf(msg_w2[k * 128 + n]);
    } else if (gid < 850) {                // W2rL
        const int idx = (gid - 722) * 256 + tid;
        const int n = idx >> 8, k = idx & 255;
        W2rL[(size_t)(k >> 5) * 4096 + n * 32 + (k & 31)] = f2bf(rmsg_w2[k * 128 + n]);
    } else if (gid < 1106) {               // UW1T: N x K
        const int idx = (gid - 850) * 256 + tid;    // [0,65536)
        const int n = idx >> 8, k = idx & 255;
        UW1T[idx] = f2bf(upd_w1[k * 256 + n]);
    } else {                               // UW2T: N x K
        const int idx = (gid - 1106) * 256 + tid;   // [0,32768)
        const int n = idx >> 8, k = idx & 255;
        UW2T[idx] = f2bf(upd_w2[k * 128 + n]);
    }
}

// ---------------------------------------------------------------------------
// Node head (verified)
// ---------------------------------------------------------------------------
__global__ __launch_bounds__(256) void node_kernel(
    const float* __restrict__ h,
    const float* __restrict__ w1, const float* __restrict__ b1,
    const float* __restrict__ w2, const float* __restrict__ b2,
    const int* __restrict__ qsz, const int* __restrict__ csz,
    float* __restrict__ plan_out, float* __restrict__ loss_out)
{
    __shared__ float qn[32][128];
    __shared__ float cn[32][128];
    __shared__ float t1[32][64];
    __shared__ float mq[32][68];
    __shared__ float mc[32][68];
    __shared__ float la[32][33];
    __shared__ float red[4];
    const int bb = blockIdx.x;
    const int tid = threadIdx.x;
    const int qs = qsz[bb], cs = csz[bb];
    for (int u = tid * 4; u < 4096; u += 1024) {
        const int p = u >> 7, d = u & 127;
        float4 zq = make_float4(0.f, 0.f, 0.f, 0.f), zc = zq;
        if (p < NPG) {
            zq = *(const float4*)(h + (size_t)((2 * bb) * NPG + p) * 128 + d);
            zc = *(const float4*)(h + (size_t)((2 * bb + 1) * NPG + p) * 128 + d);
        }
        *(float4*)&qn[p][d] = zq;
        *(float4*)&cn[p][d] = zc;
    }
    __syncthreads();
    const int col = tid & 63;
    const int rg  = tid >> 6;
    for (int s = 0; s < 2; ++s) {
        const float (*src)[128] = s ? cn : qn;
        float (*dst)[68] = s ? mc : mq;
        const int sz = s ? cs : qs;
        float a8[8];
#pragma unroll
        for (int u = 0; u < 8; ++u) a8[u] = b1[col];
        for (int k = 0; k < 128; ++k) {
            const float wv = w1[k * 64 + col];
#pragma unroll
            for (int u = 0; u < 8; ++u) a8[u] = fmaf(src[rg + 4 * u][k], wv, a8[u]);
        }
#pragma unroll
        for (int u = 0; u < 8; ++u) t1[rg + 4 * u][col] = fmaxf(a8[u], 0.f);
        __syncthreads();
#pragma unroll
        for (int u = 0; u < 8; ++u) a8[u] = b2[col];
        for (int k = 0; k < 64; ++k) {
            const float wv = w2[k * 64 + col];
#pragma unroll
            for (int u = 0; u < 8; ++u) a8[u] = fmaf(t1[rg + 4 * u][k], wv, a8[u]);
        }
#pragma unroll
        for (int u = 0; u < 8; ++u) {
            const int r = rg + 4 * u;
            dst[r][col] = (r < sz) ? a8[u] : 0.f;
        }
        __syncthreads();
    }
    {
        const int q = tid >> 3, cg = tid & 7;
#pragma unroll
        for (int u = 0; u < 4; ++u) {
            const int c = cg + 8 * u;
            float s = 0.f;
            for (int d = 0; d < 64; ++d) s = fmaf(mq[q][d], mc[c][d], s);
            la[q][c] = s * TEMPINV;
        }
    }
    __syncthreads();
    const int l8 = tid & 7, rq = tid >> 3;
    for (int it = 0; it < SINK_ITERS; ++it) {
        {
            float x[4];
#pragma unroll
            for (int u = 0; u < 4; ++u) x[u] = la[rq][l8 * 4 + u];
            float m = fmaxf(fmaxf(x[0], x[1]), fmaxf(x[2], x[3]));
            m = fmaxf(m, __shfl_xor(m, 1));
            m = fmaxf(m, __shfl_xor(m, 2));
            m = fmaxf(m, __shfl_xor(m, 4));
            float s = __expf(x[0] - m) + __expf(x[1] - m) + __expf(x[2] - m) + __expf(x[3] - m);
            s += __shfl_xor(s, 1);
            s += __shfl_xor(s, 2);
            s += __shfl_xor(s, 4);
            const float lse = m + __logf(s);
#pragma unroll
            for (int u = 0; u < 4; ++u) la[rq][l8 * 4 + u] = x[u] - lse;
        }
        __syncthreads();
        {
            float x[4];
#pragma unroll
            for (int u = 0; u < 4; ++u) x[u] = la[l8 * 4 + u][rq];
            float m = fmaxf(fmaxf(x[0], x[1]), fmaxf(x[2], x[3]));
            m = fmaxf(m, __shfl_xor(m, 1));
            m = fmaxf(m, __shfl_xor(m, 2));
            m = fmaxf(m, __shfl_xor(m, 4));
            float s = __expf(x[0] - m) + __expf(x[1] - m) + __expf(x[2] - m) + __expf(x[3] - m);
            s += __shfl_xor(s, 1);
            s += __shfl_xor(s, 2);
            s += __shfl_xor(s, 4);
            const float lse = m + __logf(s);
#pragma unroll
            for (int u = 0; u < 4; ++u) la[l8 * 4 + u][rq] = x[u] - lse;
        }
        __syncthreads();
    }
    for (int u = tid; u < 1024; u += 256) {
        const int q = u >> 5, c = u & 31;
        const float p = __expf(la[q][c]);
        la[q][c] = p;
        plan_out[(size_t)bb * 1024 + u] = p;
    }
    __syncthreads();
    float lsum = 0.f;
    {
        const int q = tid >> 3, dg = tid & 7;
        for (int u = 0; u < 16; ++u) {
            const int d = dg + 8 * u;
            float pc = 0.f;
#pragma unroll
            for (int c = 0; c < 32; ++c) pc = fmaf(la[q][c], cn[c][d], pc);
            lsum += fmaxf(qn[q][d] - pc, 0.f);
        }
    }
#pragma unroll
    for (int off = 1; off < 64; off <<= 1) lsum += __shfl_xor(lsum, off);
    if ((tid & 63) == 0) red[tid >> 6] = lsum;
    __syncthreads();
    if (tid == 0) loss_out[bb] = -(red[0] + red[1] + red[2] + red[3]);
}

// ---------------------------------------------------------------------------
// Edge head (verified)
// ---------------------------------------------------------------------------
__global__ __launch_bounds__(256) void edge_kernel(
    const float* __restrict__ plan, const float* __restrict__ EM,
    const int* __restrict__ from_idx, const int* __restrict__ to_idx,
    float* __restrict__ loss_out)
{
    __shared__ float T[32][33];
    __shared__ float la[64][65];
    __shared__ float ce[64][128];
    __shared__ int qf[64], qt[64], cfi[64], cti[64];
    __shared__ float red[4];
    const int bb = blockIdx.x;
    const int tid = threadIdx.x;
    for (int u = tid; u < 1024; u += 256) T[u >> 5][u & 31] = plan[(size_t)bb * 1024 + u];
    if (tid < 64) {
        const int gq = 2 * bb, gc = 2 * bb + 1;
        qf[tid]  = from_idx[gq * 64 + tid] - gq * NPG;
        qt[tid]  = to_idx  [gq * 64 + tid] - gq * NPG;
        cfi[tid] = from_idx[gc * 64 + tid] - gc * NPG;
        cti[tid] = to_idx  [gc * 64 + tid] - gc * NPG;
    }
    {
        const int gc = 2 * bb + 1;
        for (int u = tid * 4; u < 8192; u += 1024) {
            const int i = u >> 7, d = u & 127;
            *(float4*)&ce[i][d] = *(const float4*)(EM + (size_t)(gc * 64 + i) * 128 + d);
        }
    }
    __syncthreads();
    {
        const int i = tid >> 2, jg = tid & 3;
        const int a = qf[i], b_ = qt[i];
#pragma unroll
        for (int u = 0; u < 16; ++u) {
            const int j = jg * 16 + u;
            const float s = T[a][cfi[j]] * T[b_][cti[j]] + T[a][cti[j]] * T[b_][cfi[j]];
            la[i][j] = s * TEMPINV;
        }
    }
    __syncthreads();
    const int l4 = tid & 3, rr = tid >> 2;
    for (int it = 0; it < SINK_ITERS; ++it) {
        {
            float x[16];
#pragma unroll
            for (int u = 0; u < 16; ++u) x[u] = la[rr][l4 * 16 + u];
            float m = x[0];
#pragma unroll
            for (int u = 1; u < 16; ++u) m = fmaxf(m, x[u]);
            m = fmaxf(m, __shfl_xor(m, 1));
            m = fmaxf(m, __shfl_xor(m, 2));
            float s = 0.f;
#pragma unroll
            for (int u = 0; u < 16; ++u) s += __expf(x[u] - m);
            s += __shfl_xor(s, 1);
            s += __shfl_xor(s, 2);
            const float lse = m + __logf(s);
#pragma unroll
            for (int u = 0; u < 16; ++u) la[rr][l4 * 16 + u] = x[u] - lse;
        }
        __syncthreads();
        {
            float x[16];
#pragma unroll
            for (int u = 0; u < 16; ++u) x[u] = la[l4 * 16 + u][rr];
            float m = x[0];
#pragma unroll
            for (int u = 1; u < 16; ++u) m = fmaxf(m, x[u]);
            m = fmaxf(m, __shfl_xor(m, 1));
            m = fmaxf(m, __shfl_xor(m, 2));
            float s = 0.f;
#pragma unroll
            for (int u = 0; u < 16; ++u) s += __expf(x[u] - m);
            s += __shfl_xor(s, 1);
            s += __shfl_xor(s, 2);
            const float lse = m + __logf(s);
#pragma unroll
            for (int u = 0; u < 16; ++u) la[l4 * 16 + u][rr] = x[u] - lse;
        }
        __syncthreads();
    }
    for (int u = tid; u < 4096; u += 256) la[u >> 6][u & 63] = __expf(la[u >> 6][u & 63]);
    __syncthreads();
    float lsum = 0.f;
    {
        const int q = tid >> 2, dg = tid & 3;
        const float* qe = EM + (size_t)((2 * bb) * 64 + q) * 128;
        for (int u = 0; u < 32; ++u) {
            const int d = dg + 4 * u;
            float pc = 0.f;
            for (int c = 0; c < 64; ++c) pc = fmaf(la[q][c], ce[c][d], pc);
            lsum += fmaxf(qe[d] - pc, 0.f);
        }
    }
#pragma unroll
    for (int off = 1; off < 64; off <<= 1) lsum += __shfl_xor(lsum, off);
    if ((tid & 63) == 0) red[tid >> 6] = lsum;
    __syncthreads();
    if (tid == 0) loss_out[bb] -= CW * (red[0] + red[1] + red[2] + red[3]);
}

// ---------------------------------------------------------------------------
extern "C" void kernel_launch(void* const* d_in, const int* in_sizes, int n_in,
                              void* d_out, int out_size, void* d_ws, size_t ws_size,
                              hipStream_t stream)
{
    const float* node_features = (const float*)d_in[0];
    const float* edge_features = (const float*)d_in[1];
    const float* enc_nw  = (const float*)d_in[2];
    const float* enc_nb  = (const float*)d_in[3];
    const float* enc_ew  = (const float*)d_in[4];
    const float* enc_eb  = (const float*)d_in[5];
    const float* msg_w1  = (const float*)d_in[6];
    const float* msg_b1  = (const float*)d_in[7];
    const float* msg_w2  = (const float*)d_in[8];
    const float* msg_b2  = (const float*)d_in[9];
    const float* rmsg_w1 = (const float*)d_in[10];
    const float* rmsg_b1 = (const float*)d_in[11];
    const float* rmsg_w2 = (const float*)d_in[12];
    const float* rmsg_b2 = (const float*)d_in[13];
    const float* upd_w1  = (const float*)d_in[14];
    const float* upd_b1  = (const float*)d_in[15];
    const float* upd_w2  = (const float*)d_in[16];
    const float* upd_b2  = (const float*)d_in[17];
    const float* sk_w1   = (const float*)d_in[18];
    const float* sk_b1   = (const float*)d_in[19];
    const float* sk_w2   = (const float*)d_in[20];
    const float* sk_b2   = (const float*)d_in[21];
    const int* from_idx  = (const int*)d_in[22];
    const int* to_idx    = (const int*)d_in[23];
    const int* qsizes    = (const int*)d_in[24];
    const int* csizes    = (const int*)d_in[25];
    float* out = (float*)d_out;

    float* ws     = (float*)d_ws;
    float* h      = ws;                         // NN*128 fp32
    float* EM     = h + (size_t)NN * 128;       // NE*128 fp32
    float* plan   = EM + (size_t)NE * 128;      // NB*1024
    float* bcomb  = plan + (size_t)NB * 1024;   // 512
    ushort* WcombL = (ushort*)(bcomb + 512);    // 512*32
    ushort* encL  = WcombL + 16384;             // 128*32
    ushort* WhpL  = encL + 4096;                // 131072
    ushort* W2fL  = WhpL + 131072;              // 32768
    ushort* W2rL  = W2fL + 32768;               // 32768
    ushort* UW1T  = W2rL + 32768;               // 65536
    ushort* UW2T  = UW1T + 65536;               // 32768

    const dim3 blk(256);
    const dim3 blk512(512);

    pack2<<<1234, blk, 0, stream>>>(msg_w1, rmsg_w1, msg_b1, rmsg_b1,
                                    enc_ew, enc_eb, enc_nw, msg_w2, rmsg_w2,
                                    upd_w1, upd_w2,
                                    WcombL, bcomb, encL, WhpL, W2fL, W2rL, UW1T, UW2T);

    gnn_fused<<<dim3(NG), blk512, 0, stream>>>(
        node_features, edge_features, encL, enc_nb, WcombL, bcomb,
        WhpL, W2fL, W2rL, msg_b2, rmsg_b2,
        UW1T, upd_b1, UW2T, upd_b2, from_idx, to_idx, h, EM);

    node_kernel<<<NB, blk, 0, stream>>>(
        h, sk_w1, sk_b1, sk_w2, sk_b2, qsizes, csizes, plan, out);
    edge_kernel<<<NB, blk, 0, stream>>>(
        plan, EM, from_idx, to_idx, out);
}